// Round 1
// baseline (1159.504 us; speedup 1.0000x reference)
//
#include <hip/hip_runtime.h>
#include <math.h>

// Problem constants
#define NN 2048      // nodes per modality
#define TWO_N 4096   // total nodes
#define NE 10240     // total hyperedges (5N)
#define BB 4         // batch
#define CC 64        // input feature dim
#define HD 128       // hidden dim
#define NNZ 94208    // 2048*(7+19) + 2048*(5+13) + 2*2048

// ---------------------------------------------------------------------------
// 1) batch-mean + L2-normalize, store transposed gT[m][c][n] (f64)
// ---------------------------------------------------------------------------
__global__ void k_mean_norm(const float* __restrict__ f1, const float* __restrict__ f2,
                            double* __restrict__ gT) {
    int n = blockIdx.x;           // node
    int m = blockIdx.y;           // modality
    int c = threadIdx.x;          // 64 threads = 1 wave
    const float* f = m ? f2 : f1;
    double s = 0.0;
    for (int b = 0; b < BB; ++b) s += (double)f[((size_t)(b * NN) + n) * CC + c];
    double mean = s * 0.25;
    double sq = mean * mean;
    for (int d = 32; d >= 1; d >>= 1) sq += __shfl_xor(sq, d);
    double norm = sqrt(sq);
    if (norm < 1e-12) norm = 1e-12;
    gT[((size_t)m * CC + c) * NN + n] = mean / norm;
}

// ---------------------------------------------------------------------------
// 2) per-row top-K of cosine sim (K=19 mod1, K=13 mod2), stable (min-index tie)
//    2 rows per block (128 threads, 2 waves); sims row in LDS (f64).
// ---------------------------------------------------------------------------
__global__ void k_topk(const double* __restrict__ gT,
                       int* __restrict__ knn1, int* __restrict__ knn2) {
    __shared__ double sims[2][NN];
    __shared__ double gi[2][CC];
    int m  = blockIdx.y;
    int i0 = blockIdx.x * 2;
    const double* g = gT + (size_t)m * CC * NN;
    int tid = threadIdx.x;
    if (tid < 128) {
        int r = tid >> 6, c = tid & 63;
        gi[r][c] = g[(size_t)c * NN + (i0 + r)];
    }
    __syncthreads();
    for (int j = tid; j < NN; j += 128) {
        double d0 = 0.0, d1 = 0.0;
        #pragma unroll
        for (int c = 0; c < CC; ++c) {
            double gv = g[(size_t)c * NN + j];   // coalesced across j
            d0 += gi[0][c] * gv;
            d1 += gi[1][c] * gv;
        }
        sims[0][j] = d0; sims[1][j] = d1;
    }
    __syncthreads();
    int wave = tid >> 6, lane = tid & 63;
    int K = (m == 0) ? 19 : 13;
    int* knn = (m == 0) ? knn1 : knn2;
    int row = i0 + wave;
    double* sr = sims[wave];
    for (int t = 0; t < K; ++t) {
        double bv = -1e300; int bi = (1 << 30);
        for (int j = lane; j < NN; j += 64) {
            double vv = sr[j];
            if (vv > bv || (vv == bv && j < bi)) { bv = vv; bi = j; }
        }
        for (int d = 32; d >= 1; d >>= 1) {
            double ov = __shfl_xor(bv, d);
            int    oi = __shfl_xor(bi, d);
            if (ov > bv || (ov == bv && oi < bi)) { bv = ov; bi = oi; }
        }
        if (lane == 0) {
            knn[(size_t)row * K + t] = bi;
            sr[bi] = -1e300;   // remove from candidates
        }
        // wave-lockstep: LDS write by lane0 is ordered before next scan
    }
}

// ---------------------------------------------------------------------------
// 3) node degrees DV (row sums of H). init to 1 (inter edge), scatter-count.
// ---------------------------------------------------------------------------
__global__ void k_dv_init(int* __restrict__ DV) {
    int v = blockIdx.x * blockDim.x + threadIdx.x;
    if (v < TWO_N) DV[v] = 1;
}

__global__ void k_dv_count(const int* __restrict__ knn1, const int* __restrict__ knn2,
                           int* __restrict__ DV) {
    int id = blockIdx.x * blockDim.x + threadIdx.x;
    if (id < NN * 19) {
        int t = id % 19;
        int v = knn1[id];
        atomicAdd(&DV[v], (t < 7) ? 2 : 1);      // in both k=6 and k=18 edges
    } else if (id < NN * 19 + NN * 13) {
        int id2 = id - NN * 19;
        int t = id2 % 13;
        int v = NN + knn2[id2];
        atomicAdd(&DV[v], (t < 5) ? 2 : 1);
    }
}

// ---------------------------------------------------------------------------
// 4) exclusive scan of DV -> CSR offsets; cursor copy; dvis = 1/sqrt(DV)
//    single wave, 64 elems/lane.
// ---------------------------------------------------------------------------
__global__ void k_scan(const int* __restrict__ DV, int* __restrict__ offs,
                       int* __restrict__ cursor, double* __restrict__ dvis) {
    int lane = threadIdx.x;      // 64
    int base = lane * 64;
    int s = 0;
    for (int q = 0; q < 64; ++q) s += DV[base + q];
    int x = s;
    for (int d = 1; d < 64; d <<= 1) {
        int y = __shfl_up(x, d);
        if (lane >= d) x += y;
    }
    int run = x - s;             // exclusive prefix of lane chunk
    for (int q = 0; q < 64; ++q) {
        int v = base + q;
        offs[v] = run; cursor[v] = run;
        dvis[v] = 1.0 / sqrt((double)DV[v]);
        run += DV[v];
    }
    if (lane == 63) offs[TWO_N] = run;   // == NNZ
}

// ---------------------------------------------------------------------------
// 5) fill CSR transpose: node v -> list of edge ids containing v
//    edge id families: [0,N) m1k6 ; [N,2N) m1k18 ; [2N,3N) m2k4 ;
//                      [3N,4N) m2k12 ; [4N,5N) inter
// ---------------------------------------------------------------------------
__global__ void k_fill(const int* __restrict__ knn1, const int* __restrict__ knn2,
                       int* __restrict__ cursor, int* __restrict__ entries) {
    int id = blockIdx.x * blockDim.x + threadIdx.x;
    const int M1 = NN * 19, M2 = NN * 13;
    if (id < M1) {
        int i = id / 19, t = id % 19;
        int v = knn1[id];
        int p = atomicAdd(&cursor[v], 1); entries[p] = NN + i;       // k=18 edge
        if (t < 7) { int p2 = atomicAdd(&cursor[v], 1); entries[p2] = i; }
    } else if (id < M1 + M2) {
        int id2 = id - M1;
        int i = id2 / 13, t = id2 % 13;
        int v = NN + knn2[id2];
        int p = atomicAdd(&cursor[v], 1); entries[p] = 3 * NN + i;   // k=12 edge
        if (t < 5) { int p2 = atomicAdd(&cursor[v], 1); entries[p2] = 2 * NN + i; }
    } else if (id < M1 + M2 + TWO_N) {
        int v = id - (M1 + M2);
        int i = (v < NN) ? v : (v - NN);
        int p = atomicAdd(&cursor[v], 1); entries[p] = 4 * NN + i;   // inter edge
    }
}

// ---------------------------------------------------------------------------
// 6) y = x @ W1^T  (Fin=64, f64 accum). 8 rows/block, 128 threads (o=tid).
// ---------------------------------------------------------------------------
__global__ void k_gemm1(const float* __restrict__ f1, const float* __restrict__ f2,
                        const float* __restrict__ W1, double* __restrict__ y) {
    __shared__ float WT[CC * HD];     // WT[c*128+o]  (32 KB)
    __shared__ double xr[8][CC];      // 4 KB
    int tid = threadIdx.x;
    for (int idx = tid; idx < HD * CC; idx += 128) {
        int o = idx >> 6, c = idx & 63;
        WT[c * HD + o] = W1[idx];
    }
    int g0 = blockIdx.x * 8;          // global row = b*4096+v
    for (int idx = tid; idx < 8 * CC; idx += 128) {
        int r = idx >> 6, c = idx & 63;
        int rv = g0 + r, b = rv >> 12, v = rv & 4095;
        float val = (v < NN) ? f1[((size_t)(b * NN) + v) * CC + c]
                             : f2[((size_t)(b * NN) + (v - NN)) * CC + c];
        xr[r][c] = (double)val;
    }
    __syncthreads();
    int o = tid;
    double acc[8] = {0, 0, 0, 0, 0, 0, 0, 0};
    #pragma unroll
    for (int c = 0; c < CC; ++c) {
        double w = (double)WT[c * HD + o];
        #pragma unroll
        for (int r = 0; r < 8; ++r) acc[r] += w * xr[r][c];
    }
    for (int r = 0; r < 8; ++r) y[(size_t)(g0 + r) * HD + o] = acc[r];
}

// ---------------------------------------------------------------------------
// 7) y = z @ W2^T (Fin=128, f64 in, f64 accum). W halves staged to stay <64KB LDS.
// ---------------------------------------------------------------------------
__global__ void k_gemm2(const double* __restrict__ z, const float* __restrict__ W2,
                        double* __restrict__ y) {
    __shared__ float WTh[64 * HD];    // 32 KB, half of W2, transposed
    __shared__ double xr[8][HD];      // 8 KB
    int tid = threadIdx.x;
    int g0 = blockIdx.x * 8;
    for (int idx = tid; idx < 8 * HD; idx += 128) {
        int r = idx >> 7, c = idx & 127;
        xr[r][c] = z[(size_t)(g0 + r) * HD + c];
    }
    int o = tid;
    double acc[8] = {0, 0, 0, 0, 0, 0, 0, 0};
    for (int h = 0; h < 2; ++h) {
        __syncthreads();
        for (int idx = tid; idx < HD * 64; idx += 128) {
            int oo = idx >> 6, cl = idx & 63;
            WTh[cl * HD + oo] = W2[(size_t)oo * HD + h * 64 + cl];
        }
        __syncthreads();
        #pragma unroll
        for (int cl = 0; cl < 64; ++cl) {
            double w = (double)WTh[cl * HD + o];
            int c = h * 64 + cl;
            #pragma unroll
            for (int r = 0; r < 8; ++r) acc[r] += w * xr[r][c];
        }
    }
    for (int r = 0; r < 8; ++r) y[(size_t)(g0 + r) * HD + o] = acc[r];
}

// ---------------------------------------------------------------------------
// 8) edge stage: u[b,e,f] = DE^-2 * sum_{v in e} y[b,v,f] * dvis[v]
// ---------------------------------------------------------------------------
__global__ void k_edge(const double* __restrict__ y, const double* __restrict__ dvis,
                       const int* __restrict__ knn1, const int* __restrict__ knn2,
                       double* __restrict__ u) {
    __shared__ int mem[19];
    __shared__ double wv[19];
    int e = blockIdx.x, b = blockIdx.y, f = threadIdx.x;
    int cnt;
    if      (e < NN)     cnt = 7;
    else if (e < 2 * NN) cnt = 19;
    else if (e < 3 * NN) cnt = 5;
    else if (e < 4 * NN) cnt = 13;
    else                 cnt = 2;
    if (f < cnt) {
        int v;
        if      (e < NN)     v = knn1[(size_t)e * 19 + f];
        else if (e < 2 * NN) v = knn1[(size_t)(e - NN) * 19 + f];
        else if (e < 3 * NN) v = NN + knn2[(size_t)(e - 2 * NN) * 13 + f];
        else if (e < 4 * NN) v = NN + knn2[(size_t)(e - 3 * NN) * 13 + f];
        else                 v = (f == 0) ? (e - 4 * NN) : (e - 4 * NN + NN);
        mem[f] = v;
        wv[f] = dvis[v];
    }
    __syncthreads();
    const double* yb = y + (size_t)b * TWO_N * HD;
    double acc = 0.0;
    for (int t = 0; t < cnt; ++t)
        acc += yb[(size_t)mem[t] * HD + f] * wv[t];
    u[((size_t)b * NE + e) * HD + f] = acc / (double)(cnt * cnt);
}

// ---------------------------------------------------------------------------
// 9) node stage: z[b,v,f] = relu( dvis[v] * sum_{e in CSR[v]} u[b,e,f] )
//    layer 0 -> zbuf (f64); layer 1 -> d_out (f32, split [:,N] / [N:,])
// ---------------------------------------------------------------------------
__global__ void k_node(const double* __restrict__ u, const double* __restrict__ dvis,
                       const int* __restrict__ offs, const int* __restrict__ entries,
                       double* __restrict__ zbuf, float* __restrict__ outp, int layer) {
    int v = blockIdx.x, b = blockIdx.y, f = threadIdx.x;
    int s = offs[v], e_end = offs[v + 1];
    const double* ub = u + (size_t)b * NE * HD;
    double acc = 0.0;
    for (int p = s; p < e_end; ++p) {
        int e = entries[p];               // broadcast load
        acc += ub[(size_t)e * HD + f];
    }
    double res = dvis[v] * acc;
    if (res < 0.0) res = 0.0;
    if (layer == 0) {
        zbuf[((size_t)b * TWO_N + v) * HD + f] = res;
    } else {
        size_t o;
        if (v < NN) o = ((size_t)(b * NN + v)) * HD + f;
        else        o = (size_t)BB * NN * HD + ((size_t)(b * NN + (v - NN))) * HD + f;
        outp[o] = (float)res;
    }
}

// ---------------------------------------------------------------------------
extern "C" void kernel_launch(void* const* d_in, const int* in_sizes, int n_in,
                              void* d_out, int out_size, void* d_ws, size_t ws_size,
                              hipStream_t stream) {
    const float* f1 = (const float*)d_in[0];
    const float* f2 = (const float*)d_in[1];
    const float* W1 = (const float*)d_in[2];
    const float* W2 = (const float*)d_in[3];
    float* out = (float*)d_out;

    // bump allocator over d_ws (total ~78.5 MB)
    char* ws = (char*)d_ws;
    size_t off = 0;
    auto alloc = [&](size_t bytes) -> void* {
        void* p = ws + off;
        off = (off + bytes + 255) & ~(size_t)255;
        return p;
    };
    double* gT      = (double*)alloc((size_t)2 * CC * NN * 8);        // 2 MB
    double* ybuf    = (double*)alloc((size_t)BB * TWO_N * HD * 8);    // 16 MB
    double* zbuf    = (double*)alloc((size_t)BB * TWO_N * HD * 8);    // 16 MB
    double* ubuf    = (double*)alloc((size_t)BB * NE * HD * 8);       // 40 MB
    double* dvis    = (double*)alloc((size_t)TWO_N * 8);
    int*    knn1    = (int*)alloc((size_t)NN * 19 * 4);
    int*    knn2    = (int*)alloc((size_t)NN * 13 * 4);
    int*    DV      = (int*)alloc((size_t)TWO_N * 4);
    int*    offs    = (int*)alloc((size_t)(TWO_N + 1) * 4);
    int*    cursor  = (int*)alloc((size_t)TWO_N * 4);
    int*    entries = (int*)alloc((size_t)NNZ * 4);

    // graph construction (f64 throughout to match the f64 golden top-k decisions)
    k_mean_norm<<<dim3(NN, 2), 64, 0, stream>>>(f1, f2, gT);
    k_topk<<<dim3(NN / 2, 2), 128, 0, stream>>>(gT, knn1, knn2);
    k_dv_init<<<(TWO_N + 255) / 256, 256, 0, stream>>>(DV);
    k_dv_count<<<(NN * 19 + NN * 13 + 255) / 256, 256, 0, stream>>>(knn1, knn2, DV);
    k_scan<<<1, 64, 0, stream>>>(DV, offs, cursor, dvis);
    k_fill<<<(NN * 19 + NN * 13 + TWO_N + 255) / 256, 256, 0, stream>>>(knn1, knn2, cursor, entries);

    // layer 1
    k_gemm1<<<(BB * TWO_N) / 8, 128, 0, stream>>>(f1, f2, W1, ybuf);
    k_edge<<<dim3(NE, BB), 128, 0, stream>>>(ybuf, dvis, knn1, knn2, ubuf);
    k_node<<<dim3(TWO_N, BB), 128, 0, stream>>>(ubuf, dvis, offs, entries, zbuf, nullptr, 0);

    // layer 2
    k_gemm2<<<(BB * TWO_N) / 8, 128, 0, stream>>>(zbuf, W2, ybuf);
    k_edge<<<dim3(NE, BB), 128, 0, stream>>>(ybuf, dvis, knn1, knn2, ubuf);
    k_node<<<dim3(TWO_N, BB), 128, 0, stream>>>(ubuf, dvis, offs, entries, nullptr, out, 1);
}

// Round 2
// 539.308 us; speedup vs baseline: 2.1500x; 2.1500x over previous
//
#include <hip/hip_runtime.h>
#include <math.h>

// Problem constants
#define NN 2048      // nodes per modality
#define TWO_N 4096   // total nodes
#define NE 10240     // total hyperedges (5N)
#define BB 4         // batch
#define CC 64        // input feature dim
#define HD 128       // hidden dim
#define NNZ 94208    // 2048*(7+19) + 2048*(5+13) + 2*2048

// ---------------------------------------------------------------------------
// 1) batch-mean + L2-normalize, store transposed gT[m][c][n] (f64)
// ---------------------------------------------------------------------------
__global__ void k_mean_norm(const float* __restrict__ f1, const float* __restrict__ f2,
                            double* __restrict__ gT) {
    int n = blockIdx.x;           // node
    int m = blockIdx.y;           // modality
    int c = threadIdx.x;          // 64 threads = 1 wave
    const float* f = m ? f2 : f1;
    double s = 0.0;
    for (int b = 0; b < BB; ++b) s += (double)f[((size_t)(b * NN) + n) * CC + c];
    double mean = s * 0.25;
    double sq = mean * mean;
    for (int d = 32; d >= 1; d >>= 1) sq += __shfl_xor(sq, d);
    double norm = sqrt(sq);
    if (norm < 1e-12) norm = 1e-12;
    gT[((size_t)m * CC + c) * NN + n] = mean / norm;
}

// ---------------------------------------------------------------------------
// 2) per-row top-K (K=19 mod1, K=13 mod2), stable (min-index tie).
//    8 rows per block (512 threads = 8 waves, wave w owns row i0+w).
//    gT staged in 64-col LDS tiles; sims held in 32 f64 registers/lane.
//    Selection: K passes with (value,-index) strict-order comparator filter
//    (no removal, no LDS sims).
// ---------------------------------------------------------------------------
__global__ void __launch_bounds__(512, 1)
k_topk(const double* __restrict__ gT,
       int* __restrict__ knn1, int* __restrict__ knn2) {
    __shared__ double gtile[CC * 64];   // 32 KB: g[c][j0..j0+63]
    __shared__ double gi[8][CC];        // 4 KB: the 8 query rows
    int m  = blockIdx.y;
    int i0 = blockIdx.x * 8;
    const double* g = gT + (size_t)m * CC * NN;
    int tid  = threadIdx.x;
    int wave = tid >> 6, lane = tid & 63;

    // stage query rows: wave w, lane c -> gi[w][c]
    gi[wave][lane] = g[(size_t)lane * NN + (i0 + wave)];

    double simreg[32];
    #pragma unroll
    for (int jt = 0; jt < 32; ++jt) {
        int j0 = jt * 64;
        __syncthreads();
        // cooperative tile stage: 4096 f64, 8 per thread, coalesced
        #pragma unroll
        for (int q = 0; q < 8; ++q) {
            int idx = q * 512 + tid;
            int c = idx >> 6, jl = idx & 63;
            gtile[c * 64 + jl] = g[(size_t)c * NN + j0 + jl];
        }
        __syncthreads();
        double s = 0.0;
        #pragma unroll
        for (int c = 0; c < CC; ++c)
            s += gi[wave][c] * gtile[c * 64 + lane];   // gi: broadcast read
        simreg[jt] = s;
    }

    // selection: wave w picks top-K of its row
    int K = (m == 0) ? 19 : 13;
    int* knn = (m == 0) ? knn1 : knn2;
    int row = i0 + wave;
    double lv = 1e300; int li = -1;      // last selected (value, index)
    for (int t = 0; t < K; ++t) {
        double bv = -1e300; int bi = (1 << 30);
        #pragma unroll
        for (int r = 0; r < 32; ++r) {
            int j = r * 64 + lane;
            double v = simreg[r];
            bool cand   = (v < lv) || (v == lv && j > li);   // strictly after last pick
            bool better = (v > bv) || (v == bv && j < bi);
            if (cand && better) { bv = v; bi = j; }
        }
        #pragma unroll
        for (int d = 32; d >= 1; d >>= 1) {
            double ov = __shfl_xor(bv, d);
            int    oi = __shfl_xor(bi, d);
            if (ov > bv || (ov == bv && oi < bi)) { bv = ov; bi = oi; }
        }
        lv = bv; li = bi;
        if (lane == 0) knn[(size_t)row * K + t] = bi;
    }
}

// ---------------------------------------------------------------------------
// 3) node degrees DV (row sums of H). init to 1 (inter edge), scatter-count.
// ---------------------------------------------------------------------------
__global__ void k_dv_init(int* __restrict__ DV) {
    int v = blockIdx.x * blockDim.x + threadIdx.x;
    if (v < TWO_N) DV[v] = 1;
}

__global__ void k_dv_count(const int* __restrict__ knn1, const int* __restrict__ knn2,
                           int* __restrict__ DV) {
    int id = blockIdx.x * blockDim.x + threadIdx.x;
    if (id < NN * 19) {
        int t = id % 19;
        int v = knn1[id];
        atomicAdd(&DV[v], (t < 7) ? 2 : 1);      // in both k=6 and k=18 edges
    } else if (id < NN * 19 + NN * 13) {
        int id2 = id - NN * 19;
        int t = id2 % 13;
        int v = NN + knn2[id2];
        atomicAdd(&DV[v], (t < 5) ? 2 : 1);
    }
}

// ---------------------------------------------------------------------------
// 4) exclusive scan of DV -> CSR offsets; cursor copy; dvis = 1/sqrt(DV)
//    single wave, 64 elems/lane.
// ---------------------------------------------------------------------------
__global__ void k_scan(const int* __restrict__ DV, int* __restrict__ offs,
                       int* __restrict__ cursor, double* __restrict__ dvis) {
    int lane = threadIdx.x;      // 64
    int base = lane * 64;
    int s = 0;
    for (int q = 0; q < 64; ++q) s += DV[base + q];
    int x = s;
    for (int d = 1; d < 64; d <<= 1) {
        int y = __shfl_up(x, d);
        if (lane >= d) x += y;
    }
    int run = x - s;             // exclusive prefix of lane chunk
    for (int q = 0; q < 64; ++q) {
        int v = base + q;
        offs[v] = run; cursor[v] = run;
        dvis[v] = 1.0 / sqrt((double)DV[v]);
        run += DV[v];
    }
    if (lane == 63) offs[TWO_N] = run;   // == NNZ
}

// ---------------------------------------------------------------------------
// 5) fill CSR transpose: node v -> list of edge ids containing v
//    edge id families: [0,N) m1k6 ; [N,2N) m1k18 ; [2N,3N) m2k4 ;
//                      [3N,4N) m2k12 ; [4N,5N) inter
// ---------------------------------------------------------------------------
__global__ void k_fill(const int* __restrict__ knn1, const int* __restrict__ knn2,
                       int* __restrict__ cursor, int* __restrict__ entries) {
    int id = blockIdx.x * blockDim.x + threadIdx.x;
    const int M1 = NN * 19, M2 = NN * 13;
    if (id < M1) {
        int i = id / 19, t = id % 19;
        int v = knn1[id];
        int p = atomicAdd(&cursor[v], 1); entries[p] = NN + i;       // k=18 edge
        if (t < 7) { int p2 = atomicAdd(&cursor[v], 1); entries[p2] = i; }
    } else if (id < M1 + M2) {
        int id2 = id - M1;
        int i = id2 / 13, t = id2 % 13;
        int v = NN + knn2[id2];
        int p = atomicAdd(&cursor[v], 1); entries[p] = 3 * NN + i;   // k=12 edge
        if (t < 5) { int p2 = atomicAdd(&cursor[v], 1); entries[p2] = 2 * NN + i; }
    } else if (id < M1 + M2 + TWO_N) {
        int v = id - (M1 + M2);
        int i = (v < NN) ? v : (v - NN);
        int p = atomicAdd(&cursor[v], 1); entries[p] = 4 * NN + i;   // inter edge
    }
}

// ---------------------------------------------------------------------------
// 6) y = x @ W1^T  (Fin=64, f64 accum). 8 rows/block, 128 threads (o=tid).
// ---------------------------------------------------------------------------
__global__ void k_gemm1(const float* __restrict__ f1, const float* __restrict__ f2,
                        const float* __restrict__ W1, double* __restrict__ y) {
    __shared__ float WT[CC * HD];     // WT[c*128+o]  (32 KB)
    __shared__ double xr[8][CC];      // 4 KB
    int tid = threadIdx.x;
    for (int idx = tid; idx < HD * CC; idx += 128) {
        int o = idx >> 6, c = idx & 63;
        WT[c * HD + o] = W1[idx];
    }
    int g0 = blockIdx.x * 8;          // global row = b*4096+v
    for (int idx = tid; idx < 8 * CC; idx += 128) {
        int r = idx >> 6, c = idx & 63;
        int rv = g0 + r, b = rv >> 12, v = rv & 4095;
        float val = (v < NN) ? f1[((size_t)(b * NN) + v) * CC + c]
                             : f2[((size_t)(b * NN) + (v - NN)) * CC + c];
        xr[r][c] = (double)val;
    }
    __syncthreads();
    int o = tid;
    double acc[8] = {0, 0, 0, 0, 0, 0, 0, 0};
    #pragma unroll
    for (int c = 0; c < CC; ++c) {
        double w = (double)WT[c * HD + o];
        #pragma unroll
        for (int r = 0; r < 8; ++r) acc[r] += w * xr[r][c];
    }
    for (int r = 0; r < 8; ++r) y[(size_t)(g0 + r) * HD + o] = acc[r];
}

// ---------------------------------------------------------------------------
// 7) y = z @ W2^T (Fin=128, f64 in, f64 accum). W halves staged to stay <64KB LDS.
// ---------------------------------------------------------------------------
__global__ void k_gemm2(const double* __restrict__ z, const float* __restrict__ W2,
                        double* __restrict__ y) {
    __shared__ float WTh[64 * HD];    // 32 KB, half of W2, transposed
    __shared__ double xr[8][HD];      // 8 KB
    int tid = threadIdx.x;
    int g0 = blockIdx.x * 8;
    for (int idx = tid; idx < 8 * HD; idx += 128) {
        int r = idx >> 7, c = idx & 127;
        xr[r][c] = z[(size_t)(g0 + r) * HD + c];
    }
    int o = tid;
    double acc[8] = {0, 0, 0, 0, 0, 0, 0, 0};
    for (int h = 0; h < 2; ++h) {
        __syncthreads();
        for (int idx = tid; idx < HD * 64; idx += 128) {
            int oo = idx >> 6, cl = idx & 63;
            WTh[cl * HD + oo] = W2[(size_t)oo * HD + h * 64 + cl];
        }
        __syncthreads();
        #pragma unroll
        for (int cl = 0; cl < 64; ++cl) {
            double w = (double)WTh[cl * HD + o];
            int c = h * 64 + cl;
            #pragma unroll
            for (int r = 0; r < 8; ++r) acc[r] += w * xr[r][c];
        }
    }
    for (int r = 0; r < 8; ++r) y[(size_t)(g0 + r) * HD + o] = acc[r];
}

// ---------------------------------------------------------------------------
// 8) edge stage: u[b,e,f] = DE^-2 * sum_{v in e} y[b,v,f] * dvis[v]
// ---------------------------------------------------------------------------
__global__ void k_edge(const double* __restrict__ y, const double* __restrict__ dvis,
                       const int* __restrict__ knn1, const int* __restrict__ knn2,
                       double* __restrict__ u) {
    __shared__ int mem[19];
    __shared__ double wv[19];
    int e = blockIdx.x, b = blockIdx.y, f = threadIdx.x;
    int cnt;
    if      (e < NN)     cnt = 7;
    else if (e < 2 * NN) cnt = 19;
    else if (e < 3 * NN) cnt = 5;
    else if (e < 4 * NN) cnt = 13;
    else                 cnt = 2;
    if (f < cnt) {
        int v;
        if      (e < NN)     v = knn1[(size_t)e * 19 + f];
        else if (e < 2 * NN) v = knn1[(size_t)(e - NN) * 19 + f];
        else if (e < 3 * NN) v = NN + knn2[(size_t)(e - 2 * NN) * 13 + f];
        else if (e < 4 * NN) v = NN + knn2[(size_t)(e - 3 * NN) * 13 + f];
        else                 v = (f == 0) ? (e - 4 * NN) : (e - 4 * NN + NN);
        mem[f] = v;
        wv[f] = dvis[v];
    }
    __syncthreads();
    const double* yb = y + (size_t)b * TWO_N * HD;
    double acc = 0.0;
    for (int t = 0; t < cnt; ++t)
        acc += yb[(size_t)mem[t] * HD + f] * wv[t];
    u[((size_t)b * NE + e) * HD + f] = acc / (double)(cnt * cnt);
}

// ---------------------------------------------------------------------------
// 9) node stage: z[b,v,f] = relu( dvis[v] * sum_{e in CSR[v]} u[b,e,f] )
//    layer 0 -> zbuf (f64); layer 1 -> d_out (f32, split [:,N] / [N:,])
// ---------------------------------------------------------------------------
__global__ void k_node(const double* __restrict__ u, const double* __restrict__ dvis,
                       const int* __restrict__ offs, const int* __restrict__ entries,
                       double* __restrict__ zbuf, float* __restrict__ outp, int layer) {
    int v = blockIdx.x, b = blockIdx.y, f = threadIdx.x;
    int s = offs[v], e_end = offs[v + 1];
    const double* ub = u + (size_t)b * NE * HD;
    double acc = 0.0;
    for (int p = s; p < e_end; ++p) {
        int e = entries[p];               // broadcast load
        acc += ub[(size_t)e * HD + f];
    }
    double res = dvis[v] * acc;
    if (res < 0.0) res = 0.0;
    if (layer == 0) {
        zbuf[((size_t)b * TWO_N + v) * HD + f] = res;
    } else {
        size_t o;
        if (v < NN) o = ((size_t)(b * NN + v)) * HD + f;
        else        o = (size_t)BB * NN * HD + ((size_t)(b * NN + (v - NN))) * HD + f;
        outp[o] = (float)res;
    }
}

// ---------------------------------------------------------------------------
extern "C" void kernel_launch(void* const* d_in, const int* in_sizes, int n_in,
                              void* d_out, int out_size, void* d_ws, size_t ws_size,
                              hipStream_t stream) {
    const float* f1 = (const float*)d_in[0];
    const float* f2 = (const float*)d_in[1];
    const float* W1 = (const float*)d_in[2];
    const float* W2 = (const float*)d_in[3];
    float* out = (float*)d_out;

    // bump allocator over d_ws (total ~78.5 MB)
    char* ws = (char*)d_ws;
    size_t off = 0;
    auto alloc = [&](size_t bytes) -> void* {
        void* p = ws + off;
        off = (off + bytes + 255) & ~(size_t)255;
        return p;
    };
    double* gT      = (double*)alloc((size_t)2 * CC * NN * 8);        // 2 MB
    double* ybuf    = (double*)alloc((size_t)BB * TWO_N * HD * 8);    // 16 MB
    double* zbuf    = (double*)alloc((size_t)BB * TWO_N * HD * 8);    // 16 MB
    double* ubuf    = (double*)alloc((size_t)BB * NE * HD * 8);       // 40 MB
    double* dvis    = (double*)alloc((size_t)TWO_N * 8);
    int*    knn1    = (int*)alloc((size_t)NN * 19 * 4);
    int*    knn2    = (int*)alloc((size_t)NN * 13 * 4);
    int*    DV      = (int*)alloc((size_t)TWO_N * 4);
    int*    offs    = (int*)alloc((size_t)(TWO_N + 1) * 4);
    int*    cursor  = (int*)alloc((size_t)TWO_N * 4);
    int*    entries = (int*)alloc((size_t)NNZ * 4);

    // graph construction (f64 throughout to match the f64 golden top-k decisions)
    k_mean_norm<<<dim3(NN, 2), 64, 0, stream>>>(f1, f2, gT);
    k_topk<<<dim3(NN / 8, 2), 512, 0, stream>>>(gT, knn1, knn2);
    k_dv_init<<<(TWO_N + 255) / 256, 256, 0, stream>>>(DV);
    k_dv_count<<<(NN * 19 + NN * 13 + 255) / 256, 256, 0, stream>>>(knn1, knn2, DV);
    k_scan<<<1, 64, 0, stream>>>(DV, offs, cursor, dvis);
    k_fill<<<(NN * 19 + NN * 13 + TWO_N + 255) / 256, 256, 0, stream>>>(knn1, knn2, cursor, entries);

    // layer 1
    k_gemm1<<<(BB * TWO_N) / 8, 128, 0, stream>>>(f1, f2, W1, ybuf);
    k_edge<<<dim3(NE, BB), 128, 0, stream>>>(ybuf, dvis, knn1, knn2, ubuf);
    k_node<<<dim3(TWO_N, BB), 128, 0, stream>>>(ubuf, dvis, offs, entries, zbuf, nullptr, 0);

    // layer 2
    k_gemm2<<<(BB * TWO_N) / 8, 128, 0, stream>>>(zbuf, W2, ybuf);
    k_edge<<<dim3(NE, BB), 128, 0, stream>>>(ybuf, dvis, knn1, knn2, ubuf);
    k_node<<<dim3(TWO_N, BB), 128, 0, stream>>>(ubuf, dvis, offs, entries, nullptr, out, 1);
}

// Round 3
// 500.230 us; speedup vs baseline: 2.3179x; 1.0781x over previous
//
#include <hip/hip_runtime.h>
#include <math.h>

// Problem constants
#define NN 2048      // nodes per modality
#define TWO_N 4096   // total nodes
#define NE 10240     // total hyperedges (5N)
#define BB 4         // batch
#define CC 64        // input feature dim
#define HD 128       // hidden dim
#define NNZ 94208    // 2048*(7+19) + 2048*(5+13) + 2*2048

// ---------------------------------------------------------------------------
// 1) batch-mean + L2-normalize, store transposed gT[m][c][n] (f64)
// ---------------------------------------------------------------------------
__global__ void k_mean_norm(const float* __restrict__ f1, const float* __restrict__ f2,
                            double* __restrict__ gT) {
    int n = blockIdx.x;           // node
    int m = blockIdx.y;           // modality
    int c = threadIdx.x;          // 64 threads = 1 wave
    const float* f = m ? f2 : f1;
    double s = 0.0;
    for (int b = 0; b < BB; ++b) s += (double)f[((size_t)(b * NN) + n) * CC + c];
    double mean = s * 0.25;
    double sq = mean * mean;
    for (int d = 32; d >= 1; d >>= 1) sq += __shfl_xor(sq, d);
    double norm = sqrt(sq);
    if (norm < 1e-12) norm = 1e-12;
    gT[((size_t)m * CC + c) * NN + n] = mean / norm;
}

// ---------------------------------------------------------------------------
// 2) per-row top-K (K=19 mod1, K=13 mod2), stable (min-index tie).
//    8 rows per block (512 threads = 8 waves, wave w owns row i0+w).
//    Double-buffered 64-col gT tiles: global->reg loads for tile t+1 overlap
//    compute on tile t; regs written to the other LDS buffer after compute;
//    ONE barrier per tile. Sims in 32 f64 regs/lane; even/odd dual accumulators.
//    Selection: K passes, (value,-index) strict-order comparator filter.
// ---------------------------------------------------------------------------
__global__ void __launch_bounds__(512, 1)
k_topk(const double* __restrict__ gT,
       int* __restrict__ knn1, int* __restrict__ knn2) {
    __shared__ double gtile[2][CC * 64];   // 2 x 32 KB
    __shared__ double gi[8][CC];           // 4 KB: the 8 query rows
    int m  = blockIdx.y;
    int i0 = blockIdx.x * 8;
    const double* g = gT + (size_t)m * CC * NN;
    int tid  = threadIdx.x;
    int wave = tid >> 6, lane = tid & 63;

    // stage query rows: wave w, lane c -> gi[w][c]
    gi[wave][lane] = g[(size_t)lane * NN + (i0 + wave)];

    // prologue: tile 0 -> buffer 0
    #pragma unroll
    for (int q = 0; q < 8; ++q) {
        int idx = q * 512 + tid;
        int c = idx >> 6, jl = idx & 63;
        gtile[0][c * 64 + jl] = g[(size_t)c * NN + jl];
    }
    __syncthreads();

    double simreg[32];
    #pragma unroll
    for (int jt = 0; jt < 32; ++jt) {
        int cur = jt & 1;
        // issue next tile's global loads (overlaps with compute below)
        double pre[8];
        if (jt + 1 < 32) {
            int j0n = (jt + 1) * 64;
            #pragma unroll
            for (int q = 0; q < 8; ++q) {
                int idx = q * 512 + tid;
                int c = idx >> 6, jl = idx & 63;
                pre[q] = g[(size_t)c * NN + j0n + jl];
            }
        }
        // compute tile jt: dual accumulator breaks the serial FMA chain
        double s0 = 0.0, s1 = 0.0;
        #pragma unroll
        for (int c = 0; c < CC; c += 2) {
            s0 += gi[wave][c]     * gtile[cur][c * 64 + lane];
            s1 += gi[wave][c + 1] * gtile[cur][(c + 1) * 64 + lane];
        }
        simreg[jt] = s0 + s1;
        // commit prefetched tile to the other buffer
        if (jt + 1 < 32) {
            int nxt = cur ^ 1;
            #pragma unroll
            for (int q = 0; q < 8; ++q) {
                int idx = q * 512 + tid;
                int c = idx >> 6, jl = idx & 63;
                gtile[nxt][c * 64 + jl] = pre[q];
            }
        }
        __syncthreads();
    }

    // selection: wave w picks top-K of its row
    int K = (m == 0) ? 19 : 13;
    int* knn = (m == 0) ? knn1 : knn2;
    int row = i0 + wave;
    double lv = 1e300; int li = -1;      // last selected (value, index)
    for (int t = 0; t < K; ++t) {
        double bv = -1e300; int bi = (1 << 30);
        #pragma unroll
        for (int r = 0; r < 32; ++r) {
            int j = r * 64 + lane;
            double v = simreg[r];
            bool cand   = (v < lv) || (v == lv && j > li);   // strictly after last pick
            bool better = (v > bv) || (v == bv && j < bi);
            if (cand && better) { bv = v; bi = j; }
        }
        #pragma unroll
        for (int d = 32; d >= 1; d >>= 1) {
            double ov = __shfl_xor(bv, d);
            int    oi = __shfl_xor(bi, d);
            if (ov > bv || (ov == bv && oi < bi)) { bv = ov; bi = oi; }
        }
        lv = bv; li = bi;
        if (lane == 0) knn[(size_t)row * K + t] = bi;
    }
}

// ---------------------------------------------------------------------------
// 3) node degrees DV (row sums of H). init to 1 (inter edge), scatter-count.
// ---------------------------------------------------------------------------
__global__ void k_dv_init(int* __restrict__ DV) {
    int v = blockIdx.x * blockDim.x + threadIdx.x;
    if (v < TWO_N) DV[v] = 1;
}

__global__ void k_dv_count(const int* __restrict__ knn1, const int* __restrict__ knn2,
                           int* __restrict__ DV) {
    int id = blockIdx.x * blockDim.x + threadIdx.x;
    if (id < NN * 19) {
        int t = id % 19;
        int v = knn1[id];
        atomicAdd(&DV[v], (t < 7) ? 2 : 1);      // in both k=6 and k=18 edges
    } else if (id < NN * 19 + NN * 13) {
        int id2 = id - NN * 19;
        int t = id2 % 13;
        int v = NN + knn2[id2];
        atomicAdd(&DV[v], (t < 5) ? 2 : 1);
    }
}

// ---------------------------------------------------------------------------
// 4) exclusive scan of DV -> CSR offsets; cursor copy; dvis = 1/sqrt(DV)
// ---------------------------------------------------------------------------
__global__ void k_scan(const int* __restrict__ DV, int* __restrict__ offs,
                       int* __restrict__ cursor, double* __restrict__ dvis) {
    int lane = threadIdx.x;      // 64
    int base = lane * 64;
    int s = 0;
    for (int q = 0; q < 64; ++q) s += DV[base + q];
    int x = s;
    for (int d = 1; d < 64; d <<= 1) {
        int y = __shfl_up(x, d);
        if (lane >= d) x += y;
    }
    int run = x - s;             // exclusive prefix of lane chunk
    for (int q = 0; q < 64; ++q) {
        int v = base + q;
        offs[v] = run; cursor[v] = run;
        dvis[v] = 1.0 / sqrt((double)DV[v]);
        run += DV[v];
    }
    if (lane == 63) offs[TWO_N] = run;   // == NNZ
}

// ---------------------------------------------------------------------------
// 5) fill CSR transpose: node v -> list of edge ids containing v
// ---------------------------------------------------------------------------
__global__ void k_fill(const int* __restrict__ knn1, const int* __restrict__ knn2,
                       int* __restrict__ cursor, int* __restrict__ entries) {
    int id = blockIdx.x * blockDim.x + threadIdx.x;
    const int M1 = NN * 19, M2 = NN * 13;
    if (id < M1) {
        int i = id / 19, t = id % 19;
        int v = knn1[id];
        int p = atomicAdd(&cursor[v], 1); entries[p] = NN + i;       // k=18 edge
        if (t < 7) { int p2 = atomicAdd(&cursor[v], 1); entries[p2] = i; }
    } else if (id < M1 + M2) {
        int id2 = id - M1;
        int i = id2 / 13, t = id2 % 13;
        int v = NN + knn2[id2];
        int p = atomicAdd(&cursor[v], 1); entries[p] = 3 * NN + i;   // k=12 edge
        if (t < 5) { int p2 = atomicAdd(&cursor[v], 1); entries[p2] = 2 * NN + i; }
    } else if (id < M1 + M2 + TWO_N) {
        int v = id - (M1 + M2);
        int i = (v < NN) ? v : (v - NN);
        int p = atomicAdd(&cursor[v], 1); entries[p] = 4 * NN + i;   // inter edge
    }
}

// ---------------------------------------------------------------------------
// 6) y = x @ W1^T  (Fin=64, f64 accum, f32 store). 8 rows/block, 128 threads.
// ---------------------------------------------------------------------------
__global__ void k_gemm1(const float* __restrict__ f1, const float* __restrict__ f2,
                        const float* __restrict__ W1, float* __restrict__ y) {
    __shared__ float WT[CC * HD];     // WT[c*128+o]  (32 KB)
    __shared__ double xr[8][CC];      // 4 KB
    int tid = threadIdx.x;
    for (int idx = tid; idx < HD * CC; idx += 128) {
        int o = idx >> 6, c = idx & 63;
        WT[c * HD + o] = W1[idx];
    }
    int g0 = blockIdx.x * 8;          // global row = b*4096+v
    for (int idx = tid; idx < 8 * CC; idx += 128) {
        int r = idx >> 6, c = idx & 63;
        int rv = g0 + r, b = rv >> 12, v = rv & 4095;
        float val = (v < NN) ? f1[((size_t)(b * NN) + v) * CC + c]
                             : f2[((size_t)(b * NN) + (v - NN)) * CC + c];
        xr[r][c] = (double)val;
    }
    __syncthreads();
    int o = tid;
    double acc[8] = {0, 0, 0, 0, 0, 0, 0, 0};
    #pragma unroll
    for (int c = 0; c < CC; ++c) {
        double w = (double)WT[c * HD + o];
        #pragma unroll
        for (int r = 0; r < 8; ++r) acc[r] += w * xr[r][c];
    }
    for (int r = 0; r < 8; ++r) y[(size_t)(g0 + r) * HD + o] = (float)acc[r];
}

// ---------------------------------------------------------------------------
// 7) y = z @ W2^T (Fin=128, f32 in, f64 accum, f32 store).
// ---------------------------------------------------------------------------
__global__ void k_gemm2(const float* __restrict__ z, const float* __restrict__ W2,
                        float* __restrict__ y) {
    __shared__ float WTh[64 * HD];    // 32 KB, half of W2, transposed
    __shared__ double xr[8][HD];      // 8 KB
    int tid = threadIdx.x;
    int g0 = blockIdx.x * 8;
    for (int idx = tid; idx < 8 * HD; idx += 128) {
        int r = idx >> 7, c = idx & 127;
        xr[r][c] = (double)z[(size_t)(g0 + r) * HD + c];
    }
    int o = tid;
    double acc[8] = {0, 0, 0, 0, 0, 0, 0, 0};
    for (int h = 0; h < 2; ++h) {
        __syncthreads();
        for (int idx = tid; idx < HD * 64; idx += 128) {
            int oo = idx >> 6, cl = idx & 63;
            WTh[cl * HD + oo] = W2[(size_t)oo * HD + h * 64 + cl];
        }
        __syncthreads();
        #pragma unroll
        for (int cl = 0; cl < 64; ++cl) {
            double w = (double)WTh[cl * HD + o];
            int c = h * 64 + cl;
            #pragma unroll
            for (int r = 0; r < 8; ++r) acc[r] += w * xr[r][c];
        }
    }
    for (int r = 0; r < 8; ++r) y[(size_t)(g0 + r) * HD + o] = (float)acc[r];
}

// ---------------------------------------------------------------------------
// 8) edge stage: u[b,e,f] = DE^-2 * sum_{v in e} y[b,v,f] * dvis[v]
//    all 4 batches per block (member staging amortized, 4 indep gather chains)
// ---------------------------------------------------------------------------
__global__ void k_edge(const float* __restrict__ y, const double* __restrict__ dvis,
                       const int* __restrict__ knn1, const int* __restrict__ knn2,
                       float* __restrict__ u) {
    __shared__ int mem[19];
    __shared__ double wv[19];
    int e = blockIdx.x, f = threadIdx.x;
    int cnt;
    if      (e < NN)     cnt = 7;
    else if (e < 2 * NN) cnt = 19;
    else if (e < 3 * NN) cnt = 5;
    else if (e < 4 * NN) cnt = 13;
    else                 cnt = 2;
    if (f < cnt) {
        int v;
        if      (e < NN)     v = knn1[(size_t)e * 19 + f];
        else if (e < 2 * NN) v = knn1[(size_t)(e - NN) * 19 + f];
        else if (e < 3 * NN) v = NN + knn2[(size_t)(e - 2 * NN) * 13 + f];
        else if (e < 4 * NN) v = NN + knn2[(size_t)(e - 3 * NN) * 13 + f];
        else                 v = (f == 0) ? (e - 4 * NN) : (e - 4 * NN + NN);
        mem[f] = v;
        wv[f] = dvis[v];
    }
    __syncthreads();
    double acc[BB] = {0, 0, 0, 0};
    for (int t = 0; t < cnt; ++t) {
        double w = wv[t];
        size_t base = (size_t)mem[t] * HD + f;
        #pragma unroll
        for (int b = 0; b < BB; ++b)
            acc[b] += (double)y[(size_t)b * TWO_N * HD + base] * w;
    }
    double inv = 1.0 / (double)(cnt * cnt);
    #pragma unroll
    for (int b = 0; b < BB; ++b)
        u[((size_t)b * NE + e) * HD + f] = (float)(acc[b] * inv);
}

// ---------------------------------------------------------------------------
// 9) node stage: z[b,v,f] = relu( dvis[v] * sum_{e in CSR[v]} u[b,e,f] )
//    all 4 batches per block; layer 0 -> zbuf f32; layer 1 -> d_out f32 split
// ---------------------------------------------------------------------------
__global__ void k_node(const float* __restrict__ u, const double* __restrict__ dvis,
                       const int* __restrict__ offs, const int* __restrict__ entries,
                       float* __restrict__ zbuf, float* __restrict__ outp, int layer) {
    int v = blockIdx.x, f = threadIdx.x;
    int s = offs[v], e_end = offs[v + 1];
    double acc[BB] = {0, 0, 0, 0};
    for (int p = s; p < e_end; ++p) {
        int e = entries[p];               // broadcast load
        size_t base = (size_t)e * HD + f;
        #pragma unroll
        for (int b = 0; b < BB; ++b)
            acc[b] += (double)u[(size_t)b * NE * HD + base];
    }
    double dv = dvis[v];
    #pragma unroll
    for (int b = 0; b < BB; ++b) {
        double res = dv * acc[b];
        if (res < 0.0) res = 0.0;
        if (layer == 0) {
            zbuf[((size_t)b * TWO_N + v) * HD + f] = (float)res;
        } else {
            size_t o;
            if (v < NN) o = ((size_t)(b * NN + v)) * HD + f;
            else        o = (size_t)BB * NN * HD + ((size_t)(b * NN + (v - NN))) * HD + f;
            outp[o] = (float)res;
        }
    }
}

// ---------------------------------------------------------------------------
extern "C" void kernel_launch(void* const* d_in, const int* in_sizes, int n_in,
                              void* d_out, int out_size, void* d_ws, size_t ws_size,
                              hipStream_t stream) {
    const float* f1 = (const float*)d_in[0];
    const float* f2 = (const float*)d_in[1];
    const float* W1 = (const float*)d_in[2];
    const float* W2 = (const float*)d_in[3];
    float* out = (float*)d_out;

    // bump allocator over d_ws
    char* ws = (char*)d_ws;
    size_t off = 0;
    auto alloc = [&](size_t bytes) -> void* {
        void* p = ws + off;
        off = (off + bytes + 255) & ~(size_t)255;
        return p;
    };
    double* gT      = (double*)alloc((size_t)2 * CC * NN * 8);        // 2 MB
    float*  ybuf    = (float*)alloc((size_t)BB * TWO_N * HD * 4);     // 8 MB
    float*  zbuf    = (float*)alloc((size_t)BB * TWO_N * HD * 4);     // 8 MB
    float*  ubuf    = (float*)alloc((size_t)BB * NE * HD * 4);        // 20 MB
    double* dvis    = (double*)alloc((size_t)TWO_N * 8);
    int*    knn1    = (int*)alloc((size_t)NN * 19 * 4);
    int*    knn2    = (int*)alloc((size_t)NN * 13 * 4);
    int*    DV      = (int*)alloc((size_t)TWO_N * 4);
    int*    offs    = (int*)alloc((size_t)(TWO_N + 1) * 4);
    int*    cursor  = (int*)alloc((size_t)TWO_N * 4);
    int*    entries = (int*)alloc((size_t)NNZ * 4);

    // graph construction (f64 throughout: top-k selection decisions must match
    // the f64 golden; conv intermediates are f32-stored / f64-accumulated)
    k_mean_norm<<<dim3(NN, 2), 64, 0, stream>>>(f1, f2, gT);
    k_topk<<<dim3(NN / 8, 2), 512, 0, stream>>>(gT, knn1, knn2);
    k_dv_init<<<(TWO_N + 255) / 256, 256, 0, stream>>>(DV);
    k_dv_count<<<(NN * 19 + NN * 13 + 255) / 256, 256, 0, stream>>>(knn1, knn2, DV);
    k_scan<<<1, 64, 0, stream>>>(DV, offs, cursor, dvis);
    k_fill<<<(NN * 19 + NN * 13 + TWO_N + 255) / 256, 256, 0, stream>>>(knn1, knn2, cursor, entries);

    // layer 1
    k_gemm1<<<(BB * TWO_N) / 8, 128, 0, stream>>>(f1, f2, W1, ybuf);
    k_edge<<<NE, 128, 0, stream>>>(ybuf, dvis, knn1, knn2, ubuf);
    k_node<<<TWO_N, 128, 0, stream>>>(ubuf, dvis, offs, entries, zbuf, nullptr, 0);

    // layer 2
    k_gemm2<<<(BB * TWO_N) / 8, 128, 0, stream>>>(zbuf, W2, ybuf);
    k_edge<<<NE, 128, 0, stream>>>(ybuf, dvis, knn1, knn2, ubuf);
    k_node<<<TWO_N, 128, 0, stream>>>(ubuf, dvis, offs, entries, nullptr, out, 1);
}

// Round 4
// 397.208 us; speedup vs baseline: 2.9191x; 1.2594x over previous
//
#include <hip/hip_runtime.h>
#include <math.h>

// Problem constants
#define NN 2048      // nodes per modality
#define TWO_N 4096   // total nodes
#define NE 10240     // total hyperedges (5N)
#define BB 4         // batch
#define CC 64        // input feature dim
#define HD 128       // hidden dim
#define NNZ 94208    // 2048*(7+19) + 2048*(5+13) + 2*2048
#define CANDCAP 32   // max top-k candidates per row after f32 margin filter

// ---------------------------------------------------------------------------
// 1) batch-mean + L2-normalize.
//    Outputs: g32T[m][c][n] f32 (for the f32 sims GEMM, col-major staging)
//             gR64[m][n][c] f64 (row-major, for the exact refine pass)
// ---------------------------------------------------------------------------
__global__ void k_mean_norm(const float* __restrict__ f1, const float* __restrict__ f2,
                            float* __restrict__ g32T, double* __restrict__ gR64) {
    int n = blockIdx.x;           // node
    int m = blockIdx.y;           // modality
    int c = threadIdx.x;          // 64 threads = 1 wave
    const float* f = m ? f2 : f1;
    double s = 0.0;
    for (int b = 0; b < BB; ++b) s += (double)f[((size_t)(b * NN) + n) * CC + c];
    double mean = s * 0.25;
    double sq = mean * mean;
    for (int d = 32; d >= 1; d >>= 1) sq += __shfl_xor(sq, d);
    double norm = sqrt(sq);
    if (norm < 1e-12) norm = 1e-12;
    double g = mean / norm;
    g32T[((size_t)m * CC + c) * NN + n] = (float)g;
    gR64[((size_t)m * NN + n) * CC + c] = g;
}

// ---------------------------------------------------------------------------
// 2) f32 sims GEMM: sims[m] = G32 * G32^T  (2048x2048, K=64).
//    64x64 output tile per block, 256 threads, each 4x4 register tile.
//    LDS 32 KB (As+Bs). VALU-bound: 16 FMA per 2 ds_read_b128.
// ---------------------------------------------------------------------------
__global__ void __launch_bounds__(256)
k_sims(const float* __restrict__ g32T, float* __restrict__ sims) {
    __shared__ float As[CC][64];   // As[k][r], 16 KB
    __shared__ float Bs[CC][64];   // Bs[k][j], 16 KB
    int m  = blockIdx.y;
    int bi = blockIdx.x >> 5, bj = blockIdx.x & 31;
    int i0 = bi * 64, j0 = bj * 64;
    const float* g = g32T + (size_t)m * CC * NN;
    int tid = threadIdx.x;
    #pragma unroll
    for (int q = 0; q < 16; ++q) {
        int idx = q * 256 + tid;
        int k = idx >> 6, r = idx & 63;
        As[k][r] = g[(size_t)k * NN + i0 + r];
        Bs[k][r] = g[(size_t)k * NN + j0 + r];
    }
    __syncthreads();
    int tr = tid >> 4, tc = tid & 15;
    float acc[4][4] = {{0.f}};
    #pragma unroll
    for (int k = 0; k < CC; ++k) {
        float4 a = *((const float4*)&As[k][tr << 2]);
        float4 b = *((const float4*)&Bs[k][tc << 2]);
        acc[0][0] += a.x * b.x; acc[0][1] += a.x * b.y; acc[0][2] += a.x * b.z; acc[0][3] += a.x * b.w;
        acc[1][0] += a.y * b.x; acc[1][1] += a.y * b.y; acc[1][2] += a.y * b.z; acc[1][3] += a.y * b.w;
        acc[2][0] += a.z * b.x; acc[2][1] += a.z * b.y; acc[2][2] += a.z * b.z; acc[2][3] += a.z * b.w;
        acc[3][0] += a.w * b.x; acc[3][1] += a.w * b.y; acc[3][2] += a.w * b.z; acc[3][3] += a.w * b.w;
    }
    float* srow = sims + (size_t)m * NN * NN;
    #pragma unroll
    for (int x = 0; x < 4; ++x) {
        float4 v = make_float4(acc[x][0], acc[x][1], acc[x][2], acc[x][3]);
        *((float4*)&srow[(size_t)(i0 + (tr << 2) + x) * NN + j0 + (tc << 2)]) = v;
    }
}

// ---------------------------------------------------------------------------
// 3) f32 top-K + margin candidate capture.
//    1 wave per row; 2048 sims in 32 regs/lane; K comparator-filter passes
//    (strict (value,-index) order). Then collect ALL j with s >= vK - delta.
//    delta = 1e-5 >= 2*eps where eps <= 66*2^-24*|a||b| = 4.2e-6 (rows unit-norm)
//    => candidate set provably contains the true f64 top-K.
// ---------------------------------------------------------------------------
__global__ void __launch_bounds__(512)
k_select(const float* __restrict__ sims, int* __restrict__ cand, int* __restrict__ cntb) {
    int wave = threadIdx.x >> 6, lane = threadIdx.x & 63;
    int row = blockIdx.x * 8 + wave;    // 0..4095
    int m = row >> 11, i = row & 2047;
    int K = m ? 13 : 19;
    const float* s = sims + (size_t)m * NN * NN + (size_t)i * NN;
    float sv[32];
    #pragma unroll
    for (int q = 0; q < 8; ++q) {
        float4 v = *((const float4*)&s[q * 256 + (lane << 2)]);
        sv[q * 4 + 0] = v.x; sv[q * 4 + 1] = v.y; sv[q * 4 + 2] = v.z; sv[q * 4 + 3] = v.w;
    }
    // element r of lane: j = (r>>2)*256 + lane*4 + (r&3)
    float lv = 3.0e38f; int li = -1;
    for (int t = 0; t < K; ++t) {
        float bv = -3.0e38f; int bi = (1 << 30);
        #pragma unroll
        for (int r = 0; r < 32; ++r) {
            int j = ((r >> 2) << 8) + (lane << 2) + (r & 3);
            float v = sv[r];
            bool cnd    = (v < lv) || (v == lv && j > li);   // strictly after last pick
            bool better = (v > bv) || (v == bv && j < bi);
            if (cnd && better) { bv = v; bi = j; }
        }
        #pragma unroll
        for (int d = 32; d >= 1; d >>= 1) {
            float ov = __shfl_xor(bv, d);
            int   oi = __shfl_xor(bi, d);
            if (ov > bv || (ov == bv && oi < bi)) { bv = ov; bi = oi; }
        }
        lv = bv; li = bi;
    }
    float thr = lv - 1e-5f;              // lv == f32 K-th value
    unsigned long long ltmask = (lane == 0) ? 0ull : ((~0ull) >> (64 - lane));
    int base = 0;
    int* crow = cand + (size_t)row * CANDCAP;
    #pragma unroll
    for (int r = 0; r < 32; ++r) {
        int j = ((r >> 2) << 8) + (lane << 2) + (r & 3);
        bool p = sv[r] >= thr;
        unsigned long long mk = __ballot(p);
        int ofs = base + __popcll(mk & ltmask);
        if (p && ofs < CANDCAP) crow[ofs] = j;
        base += __popcll(mk);
    }
    if (lane == 0) cntb[row] = (base < CANDCAP) ? base : CANDCAP;
}

// ---------------------------------------------------------------------------
// 4) exact f64 refine: per row, f64 dots for candidates, exact rank placement
//    by (value desc, index asc) -> byte-identical knn to a full-f64 top-k.
// ---------------------------------------------------------------------------
__global__ void k_refine(const double* __restrict__ gR64,
                         const int* __restrict__ cand, const int* __restrict__ cntb,
                         int* __restrict__ knn1, int* __restrict__ knn2) {
    __shared__ double dots[CANDCAP];
    int row = blockIdx.x, lane = threadIdx.x;   // 64 threads
    int m = row >> 11, i = row & 2047;
    int K = m ? 13 : 19;
    int cnt = cntb[row]; if (cnt > CANDCAP) cnt = CANDCAP;
    const double* gm = gR64 + (size_t)m * NN * CC;
    const int* crow = cand + (size_t)row * CANDCAP;
    double qc = gm[(size_t)i * CC + lane];
    for (int t = 0; t < cnt; ++t) {
        int j = crow[t];
        double p = qc * gm[(size_t)j * CC + lane];
        #pragma unroll
        for (int d = 32; d >= 1; d >>= 1) p += __shfl_xor(p, d);
        if (lane == 0) dots[t] = p;
    }
    __syncthreads();
    int* knn = m ? knn2 : knn1;
    if (lane < cnt) {
        double vt = dots[lane]; int jt = crow[lane];
        int rank = 0;
        for (int s = 0; s < cnt; ++s) {
            double vs = dots[s]; int js = crow[s];
            if (vs > vt || (vs == vt && js < jt)) ++rank;
        }
        if (rank < K) knn[(size_t)i * K + rank] = jt;
    }
}

// ---------------------------------------------------------------------------
// 5) node degrees DV (row sums of H). init to 1 (inter edge), scatter-count.
// ---------------------------------------------------------------------------
__global__ void k_dv_init(int* __restrict__ DV) {
    int v = blockIdx.x * blockDim.x + threadIdx.x;
    if (v < TWO_N) DV[v] = 1;
}

__global__ void k_dv_count(const int* __restrict__ knn1, const int* __restrict__ knn2,
                           int* __restrict__ DV) {
    int id = blockIdx.x * blockDim.x + threadIdx.x;
    if (id < NN * 19) {
        int t = id % 19;
        int v = knn1[id];
        atomicAdd(&DV[v], (t < 7) ? 2 : 1);      // in both k=6 and k=18 edges
    } else if (id < NN * 19 + NN * 13) {
        int id2 = id - NN * 19;
        int t = id2 % 13;
        int v = NN + knn2[id2];
        atomicAdd(&DV[v], (t < 5) ? 2 : 1);
    }
}

// ---------------------------------------------------------------------------
// 6) exclusive scan of DV -> CSR offsets; cursor copy; dvis = 1/sqrt(DV)
// ---------------------------------------------------------------------------
__global__ void k_scan(const int* __restrict__ DV, int* __restrict__ offs,
                       int* __restrict__ cursor, double* __restrict__ dvis) {
    int lane = threadIdx.x;      // 64
    int base = lane * 64;
    int s = 0;
    for (int q = 0; q < 64; ++q) s += DV[base + q];
    int x = s;
    for (int d = 1; d < 64; d <<= 1) {
        int y = __shfl_up(x, d);
        if (lane >= d) x += y;
    }
    int run = x - s;             // exclusive prefix of lane chunk
    for (int q = 0; q < 64; ++q) {
        int v = base + q;
        offs[v] = run; cursor[v] = run;
        dvis[v] = 1.0 / sqrt((double)DV[v]);
        run += DV[v];
    }
    if (lane == 63) offs[TWO_N] = run;   // == NNZ
}

// ---------------------------------------------------------------------------
// 7) fill CSR transpose: node v -> list of edge ids containing v
// ---------------------------------------------------------------------------
__global__ void k_fill(const int* __restrict__ knn1, const int* __restrict__ knn2,
                       int* __restrict__ cursor, int* __restrict__ entries) {
    int id = blockIdx.x * blockDim.x + threadIdx.x;
    const int M1 = NN * 19, M2 = NN * 13;
    if (id < M1) {
        int i = id / 19, t = id % 19;
        int v = knn1[id];
        int p = atomicAdd(&cursor[v], 1); entries[p] = NN + i;       // k=18 edge
        if (t < 7) { int p2 = atomicAdd(&cursor[v], 1); entries[p2] = i; }
    } else if (id < M1 + M2) {
        int id2 = id - M1;
        int i = id2 / 13, t = id2 % 13;
        int v = NN + knn2[id2];
        int p = atomicAdd(&cursor[v], 1); entries[p] = 3 * NN + i;   // k=12 edge
        if (t < 5) { int p2 = atomicAdd(&cursor[v], 1); entries[p2] = 2 * NN + i; }
    } else if (id < M1 + M2 + TWO_N) {
        int v = id - (M1 + M2);
        int i = (v < NN) ? v : (v - NN);
        int p = atomicAdd(&cursor[v], 1); entries[p] = 4 * NN + i;   // inter edge
    }
}

// ---------------------------------------------------------------------------
// 8) y = x @ W1^T  (Fin=64, f64 accum, f32 store). 8 rows/block, 128 threads.
// ---------------------------------------------------------------------------
__global__ void k_gemm1(const float* __restrict__ f1, const float* __restrict__ f2,
                        const float* __restrict__ W1, float* __restrict__ y) {
    __shared__ float WT[CC * HD];     // WT[c*128+o]  (32 KB)
    __shared__ double xr[8][CC];      // 4 KB
    int tid = threadIdx.x;
    for (int idx = tid; idx < HD * CC; idx += 128) {
        int o = idx >> 6, c = idx & 63;
        WT[c * HD + o] = W1[idx];
    }
    int g0 = blockIdx.x * 8;          // global row = b*4096+v
    for (int idx = tid; idx < 8 * CC; idx += 128) {
        int r = idx >> 6, c = idx & 63;
        int rv = g0 + r, b = rv >> 12, v = rv & 4095;
        float val = (v < NN) ? f1[((size_t)(b * NN) + v) * CC + c]
                             : f2[((size_t)(b * NN) + (v - NN)) * CC + c];
        xr[r][c] = (double)val;
    }
    __syncthreads();
    int o = tid;
    double acc[8] = {0, 0, 0, 0, 0, 0, 0, 0};
    #pragma unroll
    for (int c = 0; c < CC; ++c) {
        double w = (double)WT[c * HD + o];
        #pragma unroll
        for (int r = 0; r < 8; ++r) acc[r] += w * xr[r][c];
    }
    for (int r = 0; r < 8; ++r) y[(size_t)(g0 + r) * HD + o] = (float)acc[r];
}

// ---------------------------------------------------------------------------
// 9) y = z @ W2^T (Fin=128, f32 in, f64 accum, f32 store).
// ---------------------------------------------------------------------------
__global__ void k_gemm2(const float* __restrict__ z, const float* __restrict__ W2,
                        float* __restrict__ y) {
    __shared__ float WTh[64 * HD];    // 32 KB, half of W2, transposed
    __shared__ double xr[8][HD];      // 8 KB
    int tid = threadIdx.x;
    int g0 = blockIdx.x * 8;
    for (int idx = tid; idx < 8 * HD; idx += 128) {
        int r = idx >> 7, c = idx & 127;
        xr[r][c] = (double)z[(size_t)(g0 + r) * HD + c];
    }
    int o = tid;
    double acc[8] = {0, 0, 0, 0, 0, 0, 0, 0};
    for (int h = 0; h < 2; ++h) {
        __syncthreads();
        for (int idx = tid; idx < HD * 64; idx += 128) {
            int oo = idx >> 6, cl = idx & 63;
            WTh[cl * HD + oo] = W2[(size_t)oo * HD + h * 64 + cl];
        }
        __syncthreads();
        #pragma unroll
        for (int cl = 0; cl < 64; ++cl) {
            double w = (double)WTh[cl * HD + o];
            int c = h * 64 + cl;
            #pragma unroll
            for (int r = 0; r < 8; ++r) acc[r] += w * xr[r][c];
        }
    }
    for (int r = 0; r < 8; ++r) y[(size_t)(g0 + r) * HD + o] = (float)acc[r];
}

// ---------------------------------------------------------------------------
// 10) edge stage: u[b,e,f] = DE^-2 * sum_{v in e} y[b,v,f] * dvis[v]
// ---------------------------------------------------------------------------
__global__ void k_edge(const float* __restrict__ y, const double* __restrict__ dvis,
                       const int* __restrict__ knn1, const int* __restrict__ knn2,
                       float* __restrict__ u) {
    __shared__ int mem[19];
    __shared__ double wv[19];
    int e = blockIdx.x, f = threadIdx.x;
    int cnt;
    if      (e < NN)     cnt = 7;
    else if (e < 2 * NN) cnt = 19;
    else if (e < 3 * NN) cnt = 5;
    else if (e < 4 * NN) cnt = 13;
    else                 cnt = 2;
    if (f < cnt) {
        int v;
        if      (e < NN)     v = knn1[(size_t)e * 19 + f];
        else if (e < 2 * NN) v = knn1[(size_t)(e - NN) * 19 + f];
        else if (e < 3 * NN) v = NN + knn2[(size_t)(e - 2 * NN) * 13 + f];
        else if (e < 4 * NN) v = NN + knn2[(size_t)(e - 3 * NN) * 13 + f];
        else                 v = (f == 0) ? (e - 4 * NN) : (e - 4 * NN + NN);
        mem[f] = v;
        wv[f] = dvis[v];
    }
    __syncthreads();
    double acc[BB] = {0, 0, 0, 0};
    for (int t = 0; t < cnt; ++t) {
        double w = wv[t];
        size_t base = (size_t)mem[t] * HD + f;
        #pragma unroll
        for (int b = 0; b < BB; ++b)
            acc[b] += (double)y[(size_t)b * TWO_N * HD + base] * w;
    }
    double inv = 1.0 / (double)(cnt * cnt);
    #pragma unroll
    for (int b = 0; b < BB; ++b)
        u[((size_t)b * NE + e) * HD + f] = (float)(acc[b] * inv);
}

// ---------------------------------------------------------------------------
// 11) node stage: z[b,v,f] = relu( dvis[v] * sum_{e in CSR[v]} u[b,e,f] )
// ---------------------------------------------------------------------------
__global__ void k_node(const float* __restrict__ u, const double* __restrict__ dvis,
                       const int* __restrict__ offs, const int* __restrict__ entries,
                       float* __restrict__ zbuf, float* __restrict__ outp, int layer) {
    int v = blockIdx.x, f = threadIdx.x;
    int s = offs[v], e_end = offs[v + 1];
    double acc[BB] = {0, 0, 0, 0};
    for (int p = s; p < e_end; ++p) {
        int e = entries[p];               // broadcast load
        size_t base = (size_t)e * HD + f;
        #pragma unroll
        for (int b = 0; b < BB; ++b)
            acc[b] += (double)u[(size_t)b * NE * HD + base];
    }
    double dv = dvis[v];
    #pragma unroll
    for (int b = 0; b < BB; ++b) {
        double res = dv * acc[b];
        if (res < 0.0) res = 0.0;
        if (layer == 0) {
            zbuf[((size_t)b * TWO_N + v) * HD + f] = (float)res;
        } else {
            size_t o;
            if (v < NN) o = ((size_t)(b * NN + v)) * HD + f;
            else        o = (size_t)BB * NN * HD + ((size_t)(b * NN + (v - NN))) * HD + f;
            outp[o] = (float)res;
        }
    }
}

// ---------------------------------------------------------------------------
extern "C" void kernel_launch(void* const* d_in, const int* in_sizes, int n_in,
                              void* d_out, int out_size, void* d_ws, size_t ws_size,
                              hipStream_t stream) {
    const float* f1 = (const float*)d_in[0];
    const float* f2 = (const float*)d_in[1];
    const float* W1 = (const float*)d_in[2];
    const float* W2 = (const float*)d_in[3];
    float* out = (float*)d_out;

    // bump allocator over d_ws (~72 MB)
    char* ws = (char*)d_ws;
    size_t off = 0;
    auto alloc = [&](size_t bytes) -> void* {
        void* p = ws + off;
        off = (off + bytes + 255) & ~(size_t)255;
        return p;
    };
    float*  g32T    = (float*)alloc((size_t)2 * CC * NN * 4);         // 1 MB
    double* gR64    = (double*)alloc((size_t)2 * NN * CC * 8);        // 2 MB
    float*  sims    = (float*)alloc((size_t)2 * NN * NN * 4);         // 32 MB
    float*  ybuf    = (float*)alloc((size_t)BB * TWO_N * HD * 4);     // 8 MB
    float*  zbuf    = (float*)alloc((size_t)BB * TWO_N * HD * 4);     // 8 MB
    float*  ubuf    = (float*)alloc((size_t)BB * NE * HD * 4);        // 20 MB
    double* dvis    = (double*)alloc((size_t)TWO_N * 8);
    int*    knn1    = (int*)alloc((size_t)NN * 19 * 4);
    int*    knn2    = (int*)alloc((size_t)NN * 13 * 4);
    int*    DV      = (int*)alloc((size_t)TWO_N * 4);
    int*    offs    = (int*)alloc((size_t)(TWO_N + 1) * 4);
    int*    cursor  = (int*)alloc((size_t)TWO_N * 4);
    int*    entries = (int*)alloc((size_t)NNZ * 4);
    int*    cand    = (int*)alloc((size_t)TWO_N * CANDCAP * 4);       // 512 KB
    int*    cntb    = (int*)alloc((size_t)TWO_N * 4);

    // graph construction: f32 sims + provably-exact f64 refine
    k_mean_norm<<<dim3(NN, 2), 64, 0, stream>>>(f1, f2, g32T, gR64);
    k_sims<<<dim3(32 * 32, 2), 256, 0, stream>>>(g32T, sims);
    k_select<<<TWO_N / 8, 512, 0, stream>>>(sims, cand, cntb);
    k_refine<<<TWO_N, 64, 0, stream>>>(gR64, cand, cntb, knn1, knn2);
    k_dv_init<<<(TWO_N + 255) / 256, 256, 0, stream>>>(DV);
    k_dv_count<<<(NN * 19 + NN * 13 + 255) / 256, 256, 0, stream>>>(knn1, knn2, DV);
    k_scan<<<1, 64, 0, stream>>>(DV, offs, cursor, dvis);
    k_fill<<<(NN * 19 + NN * 13 + TWO_N + 255) / 256, 256, 0, stream>>>(knn1, knn2, cursor, entries);

    // layer 1
    k_gemm1<<<(BB * TWO_N) / 8, 128, 0, stream>>>(f1, f2, W1, ybuf);
    k_edge<<<NE, 128, 0, stream>>>(ybuf, dvis, knn1, knn2, ubuf);
    k_node<<<TWO_N, 128, 0, stream>>>(ubuf, dvis, offs, entries, zbuf, nullptr, 0);

    // layer 2
    k_gemm2<<<(BB * TWO_N) / 8, 128, 0, stream>>>(zbuf, W2, ybuf);
    k_edge<<<NE, 128, 0, stream>>>(ybuf, dvis, knn1, knn2, ubuf);
    k_node<<<TWO_N, 128, 0, stream>>>(ubuf, dvis, offs, entries, nullptr, out, 1);
}

// Round 5
// 329.200 us; speedup vs baseline: 3.5222x; 1.2066x over previous
//
#include <hip/hip_runtime.h>
#include <math.h>

// Problem constants
#define NN 2048      // nodes per modality
#define TWO_N 4096   // total nodes
#define NE 10240     // total hyperedges (5N)
#define BB 4         // batch
#define CC 64        // input feature dim
#define HD 128       // hidden dim
#define NNZ 94208    // 2048*(7+19) + 2048*(5+13) + 2*2048
#define CANDCAP 32   // max top-k candidates per row after f32 margin filter

// ---------------------------------------------------------------------------
// 1) batch-mean + L2-normalize.
//    Outputs: g32T[m][c][n] f32 (for the f32 sims GEMM, col-major staging)
//             gR64[m][n][c] f64 (row-major, for the exact refine pass)
// ---------------------------------------------------------------------------
__global__ void k_mean_norm(const float* __restrict__ f1, const float* __restrict__ f2,
                            float* __restrict__ g32T, double* __restrict__ gR64) {
    int n = blockIdx.x;           // node
    int m = blockIdx.y;           // modality
    int c = threadIdx.x;          // 64 threads = 1 wave
    const float* f = m ? f2 : f1;
    double s = 0.0;
    for (int b = 0; b < BB; ++b) s += (double)f[((size_t)(b * NN) + n) * CC + c];
    double mean = s * 0.25;
    double sq = mean * mean;
    for (int d = 32; d >= 1; d >>= 1) sq += __shfl_xor(sq, d);
    double norm = sqrt(sq);
    if (norm < 1e-12) norm = 1e-12;
    double g = mean / norm;
    g32T[((size_t)m * CC + c) * NN + n] = (float)g;
    gR64[((size_t)m * NN + n) * CC + c] = g;
}

// ---------------------------------------------------------------------------
// 2) f32 sims GEMM: sims[m] = G32 * G32^T  (2048x2048, K=64).
//    64x64 output tile per block, 256 threads, each 4x4 register tile.
// ---------------------------------------------------------------------------
__global__ void __launch_bounds__(256)
k_sims(const float* __restrict__ g32T, float* __restrict__ sims) {
    __shared__ float As[CC][64];   // As[k][r], 16 KB
    __shared__ float Bs[CC][64];   // Bs[k][j], 16 KB
    int m  = blockIdx.y;
    int bi = blockIdx.x >> 5, bj = blockIdx.x & 31;
    int i0 = bi * 64, j0 = bj * 64;
    const float* g = g32T + (size_t)m * CC * NN;
    int tid = threadIdx.x;
    #pragma unroll
    for (int q = 0; q < 16; ++q) {
        int idx = q * 256 + tid;
        int k = idx >> 6, r = idx & 63;
        As[k][r] = g[(size_t)k * NN + i0 + r];
        Bs[k][r] = g[(size_t)k * NN + j0 + r];
    }
    __syncthreads();
    int tr = tid >> 4, tc = tid & 15;
    float acc[4][4] = {{0.f}};
    #pragma unroll
    for (int k = 0; k < CC; ++k) {
        float4 a = *((const float4*)&As[k][tr << 2]);
        float4 b = *((const float4*)&Bs[k][tc << 2]);
        acc[0][0] += a.x * b.x; acc[0][1] += a.x * b.y; acc[0][2] += a.x * b.z; acc[0][3] += a.x * b.w;
        acc[1][0] += a.y * b.x; acc[1][1] += a.y * b.y; acc[1][2] += a.y * b.z; acc[1][3] += a.y * b.w;
        acc[2][0] += a.z * b.x; acc[2][1] += a.z * b.y; acc[2][2] += a.z * b.z; acc[2][3] += a.z * b.w;
        acc[3][0] += a.w * b.x; acc[3][1] += a.w * b.y; acc[3][2] += a.w * b.z; acc[3][3] += a.w * b.w;
    }
    float* srow = sims + (size_t)m * NN * NN;
    #pragma unroll
    for (int x = 0; x < 4; ++x) {
        float4 v = make_float4(acc[x][0], acc[x][1], acc[x][2], acc[x][3]);
        *((float4*)&srow[(size_t)(i0 + (tr << 2) + x) * NN + j0 + (tc << 2)]) = v;
    }
}

// ---------------------------------------------------------------------------
// 3) f32 top-K + margin candidate capture.
//    delta = 1e-5 >= 2*eps, eps <= 66*2^-24 (unit-norm rows) => candidate set
//    provably contains the true f64 top-K.
// ---------------------------------------------------------------------------
__global__ void __launch_bounds__(512)
k_select(const float* __restrict__ sims, int* __restrict__ cand, int* __restrict__ cntb) {
    int wave = threadIdx.x >> 6, lane = threadIdx.x & 63;
    int row = blockIdx.x * 8 + wave;    // 0..4095
    int m = row >> 11, i = row & 2047;
    int K = m ? 13 : 19;
    const float* s = sims + (size_t)m * NN * NN + (size_t)i * NN;
    float sv[32];
    #pragma unroll
    for (int q = 0; q < 8; ++q) {
        float4 v = *((const float4*)&s[q * 256 + (lane << 2)]);
        sv[q * 4 + 0] = v.x; sv[q * 4 + 1] = v.y; sv[q * 4 + 2] = v.z; sv[q * 4 + 3] = v.w;
    }
    // element r of lane: j = (r>>2)*256 + lane*4 + (r&3)
    float lv = 3.0e38f; int li = -1;
    for (int t = 0; t < K; ++t) {
        float bv = -3.0e38f; int bi = (1 << 30);
        #pragma unroll
        for (int r = 0; r < 32; ++r) {
            int j = ((r >> 2) << 8) + (lane << 2) + (r & 3);
            float v = sv[r];
            bool cnd    = (v < lv) || (v == lv && j > li);   // strictly after last pick
            bool better = (v > bv) || (v == bv && j < bi);
            if (cnd && better) { bv = v; bi = j; }
        }
        #pragma unroll
        for (int d = 32; d >= 1; d >>= 1) {
            float ov = __shfl_xor(bv, d);
            int   oi = __shfl_xor(bi, d);
            if (ov > bv || (ov == bv && oi < bi)) { bv = ov; bi = oi; }
        }
        lv = bv; li = bi;
    }
    float thr = lv - 1e-5f;              // lv == f32 K-th value
    unsigned long long ltmask = (lane == 0) ? 0ull : ((~0ull) >> (64 - lane));
    int base = 0;
    int* crow = cand + (size_t)row * CANDCAP;
    #pragma unroll
    for (int r = 0; r < 32; ++r) {
        int j = ((r >> 2) << 8) + (lane << 2) + (r & 3);
        bool p = sv[r] >= thr;
        unsigned long long mk = __ballot(p);
        int ofs = base + __popcll(mk & ltmask);
        if (p && ofs < CANDCAP) crow[ofs] = j;
        base += __popcll(mk);
    }
    if (lane == 0) cntb[row] = (base < CANDCAP) ? base : CANDCAP;
}

// ---------------------------------------------------------------------------
// 4) exact f64 refine: per row, f64 dots for candidates, exact rank placement
// ---------------------------------------------------------------------------
__global__ void k_refine(const double* __restrict__ gR64,
                         const int* __restrict__ cand, const int* __restrict__ cntb,
                         int* __restrict__ knn1, int* __restrict__ knn2) {
    __shared__ double dots[CANDCAP];
    int row = blockIdx.x, lane = threadIdx.x;   // 64 threads
    int m = row >> 11, i = row & 2047;
    int K = m ? 13 : 19;
    int cnt = cntb[row]; if (cnt > CANDCAP) cnt = CANDCAP;
    const double* gm = gR64 + (size_t)m * NN * CC;
    const int* crow = cand + (size_t)row * CANDCAP;
    double qc = gm[(size_t)i * CC + lane];
    for (int t = 0; t < cnt; ++t) {
        int j = crow[t];
        double p = qc * gm[(size_t)j * CC + lane];
        #pragma unroll
        for (int d = 32; d >= 1; d >>= 1) p += __shfl_xor(p, d);
        if (lane == 0) dots[t] = p;
    }
    __syncthreads();
    int* knn = m ? knn2 : knn1;
    if (lane < cnt) {
        double vt = dots[lane]; int jt = crow[lane];
        int rank = 0;
        for (int s = 0; s < cnt; ++s) {
            double vs = dots[s]; int js = crow[s];
            if (vs > vt || (vs == vt && js < jt)) ++rank;
        }
        if (rank < K) knn[(size_t)i * K + rank] = jt;
    }
}

// ---------------------------------------------------------------------------
// 5) node degrees DV. init to 1 (inter edge), scatter-count.
// ---------------------------------------------------------------------------
__global__ void k_dv_init(int* __restrict__ DV) {
    int v = blockIdx.x * blockDim.x + threadIdx.x;
    if (v < TWO_N) DV[v] = 1;
}

__global__ void k_dv_count(const int* __restrict__ knn1, const int* __restrict__ knn2,
                           int* __restrict__ DV) {
    int id = blockIdx.x * blockDim.x + threadIdx.x;
    if (id < NN * 19) {
        int t = id % 19;
        int v = knn1[id];
        atomicAdd(&DV[v], (t < 7) ? 2 : 1);      // in both k=6 and k=18 edges
    } else if (id < NN * 19 + NN * 13) {
        int id2 = id - NN * 19;
        int t = id2 % 13;
        int v = NN + knn2[id2];
        atomicAdd(&DV[v], (t < 5) ? 2 : 1);
    }
}

// ---------------------------------------------------------------------------
// 6) exclusive scan of DV -> CSR offsets; cursor copy; dvis = 1/sqrt(DV)
// ---------------------------------------------------------------------------
__global__ void k_scan(const int* __restrict__ DV, int* __restrict__ offs,
                       int* __restrict__ cursor, double* __restrict__ dvis) {
    int lane = threadIdx.x;      // 64
    int base = lane * 64;
    int s = 0;
    for (int q = 0; q < 64; ++q) s += DV[base + q];
    int x = s;
    for (int d = 1; d < 64; d <<= 1) {
        int y = __shfl_up(x, d);
        if (lane >= d) x += y;
    }
    int run = x - s;             // exclusive prefix of lane chunk
    for (int q = 0; q < 64; ++q) {
        int v = base + q;
        offs[v] = run; cursor[v] = run;
        dvis[v] = 1.0 / sqrt((double)DV[v]);
        run += DV[v];
    }
    if (lane == 63) offs[TWO_N] = run;   // == NNZ
}

// ---------------------------------------------------------------------------
// 7) fill CSR transpose: node v -> list of edge ids containing v
// ---------------------------------------------------------------------------
__global__ void k_fill(const int* __restrict__ knn1, const int* __restrict__ knn2,
                       int* __restrict__ cursor, int* __restrict__ entries) {
    int id = blockIdx.x * blockDim.x + threadIdx.x;
    const int M1 = NN * 19, M2 = NN * 13;
    if (id < M1) {
        int i = id / 19, t = id % 19;
        int v = knn1[id];
        int p = atomicAdd(&cursor[v], 1); entries[p] = NN + i;       // k=18 edge
        if (t < 7) { int p2 = atomicAdd(&cursor[v], 1); entries[p2] = i; }
    } else if (id < M1 + M2) {
        int id2 = id - M1;
        int i = id2 / 13, t = id2 % 13;
        int v = NN + knn2[id2];
        int p = atomicAdd(&cursor[v], 1); entries[p] = 3 * NN + i;   // k=12 edge
        if (t < 5) { int p2 = atomicAdd(&cursor[v], 1); entries[p2] = 2 * NN + i; }
    } else if (id < M1 + M2 + TWO_N) {
        int v = id - (M1 + M2);
        int i = (v < NN) ? v : (v - NN);
        int p = atomicAdd(&cursor[v], 1); entries[p] = 4 * NN + i;   // inter edge
    }
}

// ---------------------------------------------------------------------------
// 8) y = x @ W1^T  (Fin=64, f64 accum, f32 store). 8 rows/block, 128 threads.
//    W1 staged ROW-MAJOR with +1 pad: WT[o*65+c].
//    Write banks: (o+c)%32, 2 lanes/bank (free). Read at fixed c across lanes
//    o: stride 65 -> bank (o+c)%32, 2-way (free).  [was: 64-way conflict]
// ---------------------------------------------------------------------------
__global__ void k_gemm1(const float* __restrict__ f1, const float* __restrict__ f2,
                        const float* __restrict__ W1, float* __restrict__ y) {
    __shared__ float WT[HD * 65];     // 33.3 KB, row-major padded
    __shared__ double xr[8][CC];      // 4 KB
    int tid = threadIdx.x;
    for (int idx = tid * 4; idx < HD * CC; idx += 128 * 4) {
        float4 w4 = *((const float4*)&W1[idx]);   // coalesced 16B
        int o = idx >> 6, c = idx & 63;
        WT[o * 65 + c + 0] = w4.x;
        WT[o * 65 + c + 1] = w4.y;
        WT[o * 65 + c + 2] = w4.z;
        WT[o * 65 + c + 3] = w4.w;
    }
    int g0 = blockIdx.x * 8;          // global row = b*4096+v
    for (int idx = tid; idx < 8 * CC; idx += 128) {
        int r = idx >> 6, c = idx & 63;
        int rv = g0 + r, b = rv >> 12, v = rv & 4095;
        float val = (v < NN) ? f1[((size_t)(b * NN) + v) * CC + c]
                             : f2[((size_t)(b * NN) + (v - NN)) * CC + c];
        xr[r][c] = (double)val;
    }
    __syncthreads();
    int o = tid;
    double acc[8] = {0, 0, 0, 0, 0, 0, 0, 0};
    #pragma unroll
    for (int c = 0; c < CC; ++c) {
        double w = (double)WT[o * 65 + c];
        #pragma unroll
        for (int r = 0; r < 8; ++r) acc[r] += w * xr[r][c];
    }
    for (int r = 0; r < 8; ++r) y[(size_t)(g0 + r) * HD + o] = (float)acc[r];
}

// ---------------------------------------------------------------------------
// 9) y = z @ W2^T (Fin=128, f32 in, f64 accum, f32 store).
//    W2 staged per-64-col half, row-major padded: WTh[o*65+cl]. Conflict-free.
// ---------------------------------------------------------------------------
__global__ void k_gemm2(const float* __restrict__ z, const float* __restrict__ W2,
                        float* __restrict__ y) {
    __shared__ float WTh[HD * 65];    // 33.3 KB, half of W2 (64 cols), padded
    __shared__ double xr[8][HD];      // 8 KB
    int tid = threadIdx.x;
    int g0 = blockIdx.x * 8;
    for (int idx = tid; idx < 8 * HD; idx += 128) {
        int r = idx >> 7, c = idx & 127;
        xr[r][c] = (double)z[(size_t)(g0 + r) * HD + c];
    }
    int o = tid;
    double acc[8] = {0, 0, 0, 0, 0, 0, 0, 0};
    for (int h = 0; h < 2; ++h) {
        __syncthreads();
        for (int idx = tid * 4; idx < HD * 64; idx += 128 * 4) {
            int oo = idx >> 6, cl = idx & 63;
            float4 w4 = *((const float4*)&W2[(size_t)oo * HD + h * 64 + cl]);
            WTh[oo * 65 + cl + 0] = w4.x;
            WTh[oo * 65 + cl + 1] = w4.y;
            WTh[oo * 65 + cl + 2] = w4.z;
            WTh[oo * 65 + cl + 3] = w4.w;
        }
        __syncthreads();
        #pragma unroll
        for (int cl = 0; cl < 64; ++cl) {
            double w = (double)WTh[o * 65 + cl];
            int c = h * 64 + cl;
            #pragma unroll
            for (int r = 0; r < 8; ++r) acc[r] += w * xr[r][c];
        }
    }
    for (int r = 0; r < 8; ++r) y[(size_t)(g0 + r) * HD + o] = (float)acc[r];
}

// ---------------------------------------------------------------------------
// 10) edge stage: u[b,e,f] = DE^-2 * sum_{v in e} y[b,v,f] * dvis[v]
// ---------------------------------------------------------------------------
__global__ void k_edge(const float* __restrict__ y, const double* __restrict__ dvis,
                       const int* __restrict__ knn1, const int* __restrict__ knn2,
                       float* __restrict__ u) {
    __shared__ int mem[19];
    __shared__ double wv[19];
    int e = blockIdx.x, f = threadIdx.x;
    int cnt;
    if      (e < NN)     cnt = 7;
    else if (e < 2 * NN) cnt = 19;
    else if (e < 3 * NN) cnt = 5;
    else if (e < 4 * NN) cnt = 13;
    else                 cnt = 2;
    if (f < cnt) {
        int v;
        if      (e < NN)     v = knn1[(size_t)e * 19 + f];
        else if (e < 2 * NN) v = knn1[(size_t)(e - NN) * 19 + f];
        else if (e < 3 * NN) v = NN + knn2[(size_t)(e - 2 * NN) * 13 + f];
        else if (e < 4 * NN) v = NN + knn2[(size_t)(e - 3 * NN) * 13 + f];
        else                 v = (f == 0) ? (e - 4 * NN) : (e - 4 * NN + NN);
        mem[f] = v;
        wv[f] = dvis[v];
    }
    __syncthreads();
    double acc[BB] = {0, 0, 0, 0};
    for (int t = 0; t < cnt; ++t) {
        double w = wv[t];
        size_t base = (size_t)mem[t] * HD + f;
        #pragma unroll
        for (int b = 0; b < BB; ++b)
            acc[b] += (double)y[(size_t)b * TWO_N * HD + base] * w;
    }
    double inv = 1.0 / (double)(cnt * cnt);
    #pragma unroll
    for (int b = 0; b < BB; ++b)
        u[((size_t)b * NE + e) * HD + f] = (float)(acc[b] * inv);
}

// ---------------------------------------------------------------------------
// 11) node stage: z[b,v,f] = relu( dvis[v] * sum_{e in CSR[v]} u[b,e,f] )
// ---------------------------------------------------------------------------
__global__ void k_node(const float* __restrict__ u, const double* __restrict__ dvis,
                       const int* __restrict__ offs, const int* __restrict__ entries,
                       float* __restrict__ zbuf, float* __restrict__ outp, int layer) {
    int v = blockIdx.x, f = threadIdx.x;
    int s = offs[v], e_end = offs[v + 1];
    double acc[BB] = {0, 0, 0, 0};
    for (int p = s; p < e_end; ++p) {
        int e = entries[p];               // broadcast load
        size_t base = (size_t)e * HD + f;
        #pragma unroll
        for (int b = 0; b < BB; ++b)
            acc[b] += (double)u[(size_t)b * NE * HD + base];
    }
    double dv = dvis[v];
    #pragma unroll
    for (int b = 0; b < BB; ++b) {
        double res = dv * acc[b];
        if (res < 0.0) res = 0.0;
        if (layer == 0) {
            zbuf[((size_t)b * TWO_N + v) * HD + f] = (float)res;
        } else {
            size_t o;
            if (v < NN) o = ((size_t)(b * NN + v)) * HD + f;
            else        o = (size_t)BB * NN * HD + ((size_t)(b * NN + (v - NN))) * HD + f;
            outp[o] = (float)res;
        }
    }
}

// ---------------------------------------------------------------------------
extern "C" void kernel_launch(void* const* d_in, const int* in_sizes, int n_in,
                              void* d_out, int out_size, void* d_ws, size_t ws_size,
                              hipStream_t stream) {
    const float* f1 = (const float*)d_in[0];
    const float* f2 = (const float*)d_in[1];
    const float* W1 = (const float*)d_in[2];
    const float* W2 = (const float*)d_in[3];
    float* out = (float*)d_out;

    // bump allocator over d_ws (~72 MB)
    char* ws = (char*)d_ws;
    size_t off = 0;
    auto alloc = [&](size_t bytes) -> void* {
        void* p = ws + off;
        off = (off + bytes + 255) & ~(size_t)255;
        return p;
    };
    float*  g32T    = (float*)alloc((size_t)2 * CC * NN * 4);         // 1 MB
    double* gR64    = (double*)alloc((size_t)2 * NN * CC * 8);        // 2 MB
    float*  sims    = (float*)alloc((size_t)2 * NN * NN * 4);         // 32 MB
    float*  ybuf    = (float*)alloc((size_t)BB * TWO_N * HD * 4);     // 8 MB
    float*  zbuf    = (float*)alloc((size_t)BB * TWO_N * HD * 4);     // 8 MB
    float*  ubuf    = (float*)alloc((size_t)BB * NE * HD * 4);        // 20 MB
    double* dvis    = (double*)alloc((size_t)TWO_N * 8);
    int*    knn1    = (int*)alloc((size_t)NN * 19 * 4);
    int*    knn2    = (int*)alloc((size_t)NN * 13 * 4);
    int*    DV      = (int*)alloc((size_t)TWO_N * 4);
    int*    offs    = (int*)alloc((size_t)(TWO_N + 1) * 4);
    int*    cursor  = (int*)alloc((size_t)TWO_N * 4);
    int*    entries = (int*)alloc((size_t)NNZ * 4);
    int*    cand    = (int*)alloc((size_t)TWO_N * CANDCAP * 4);       // 512 KB
    int*    cntb    = (int*)alloc((size_t)TWO_N * 4);

    // graph construction: f32 sims + provably-exact f64 refine
    k_mean_norm<<<dim3(NN, 2), 64, 0, stream>>>(f1, f2, g32T, gR64);
    k_sims<<<dim3(32 * 32, 2), 256, 0, stream>>>(g32T, sims);
    k_select<<<TWO_N / 8, 512, 0, stream>>>(sims, cand, cntb);
    k_refine<<<TWO_N, 64, 0, stream>>>(gR64, cand, cntb, knn1, knn2);
    k_dv_init<<<(TWO_N + 255) / 256, 256, 0, stream>>>(DV);
    k_dv_count<<<(NN * 19 + NN * 13 + 255) / 256, 256, 0, stream>>>(knn1, knn2, DV);
    k_scan<<<1, 64, 0, stream>>>(DV, offs, cursor, dvis);
    k_fill<<<(NN * 19 + NN * 13 + TWO_N + 255) / 256, 256, 0, stream>>>(knn1, knn2, cursor, entries);

    // layer 1
    k_gemm1<<<(BB * TWO_N) / 8, 128, 0, stream>>>(f1, f2, W1, ybuf);
    k_edge<<<NE, 128, 0, stream>>>(ybuf, dvis, knn1, knn2, ubuf);
    k_node<<<TWO_N, 128, 0, stream>>>(ubuf, dvis, offs, entries, zbuf, nullptr, 0);

    // layer 2
    k_gemm2<<<(BB * TWO_N) / 8, 128, 0, stream>>>(zbuf, W2, ybuf);
    k_edge<<<NE, 128, 0, stream>>>(ybuf, dvis, knn1, knn2, ubuf);
    k_node<<<TWO_N, 128, 0, stream>>>(ubuf, dvis, offs, entries, nullptr, out, 1);
}

// Round 6
// 286.850 us; speedup vs baseline: 4.0422x; 1.1476x over previous
//
#include <hip/hip_runtime.h>
#include <math.h>

// Problem constants
#define NN 2048      // nodes per modality
#define TWO_N 4096   // total nodes
#define NE 10240     // total hyperedges (5N)
#define BB 4         // batch
#define CC 64        // input feature dim
#define HD 128       // hidden dim
#define NNZ 94208    // 2048*(7+19) + 2048*(5+13) + 2*2048
#define CANDCAP 32   // max top-k candidates per row after f32 margin filter

// ---------------------------------------------------------------------------
// 1) batch-mean + L2-normalize.
//    Outputs: g32T[m][c][n] f32 (for the f32 sims GEMM, col-major staging)
//             gR64[m][n][c] f64 (row-major, for the exact refine pass)
// ---------------------------------------------------------------------------
__global__ void k_mean_norm(const float* __restrict__ f1, const float* __restrict__ f2,
                            float* __restrict__ g32T, double* __restrict__ gR64) {
    int n = blockIdx.x;           // node
    int m = blockIdx.y;           // modality
    int c = threadIdx.x;          // 64 threads = 1 wave
    const float* f = m ? f2 : f1;
    double s = 0.0;
    for (int b = 0; b < BB; ++b) s += (double)f[((size_t)(b * NN) + n) * CC + c];
    double mean = s * 0.25;
    double sq = mean * mean;
    for (int d = 32; d >= 1; d >>= 1) sq += __shfl_xor(sq, d);
    double norm = sqrt(sq);
    if (norm < 1e-12) norm = 1e-12;
    double g = mean / norm;
    g32T[((size_t)m * CC + c) * NN + n] = (float)g;
    gR64[((size_t)m * NN + n) * CC + c] = g;
}

// ---------------------------------------------------------------------------
// 2) f32 sims GEMM: sims[m] = G32 * G32^T  (2048x2048, K=64).
//    64x64 output tile per block, 256 threads, each 4x4 register tile.
// ---------------------------------------------------------------------------
__global__ void __launch_bounds__(256)
k_sims(const float* __restrict__ g32T, float* __restrict__ sims) {
    __shared__ float As[CC][64];   // As[k][r], 16 KB
    __shared__ float Bs[CC][64];   // Bs[k][j], 16 KB
    int m  = blockIdx.y;
    int bi = blockIdx.x >> 5, bj = blockIdx.x & 31;
    int i0 = bi * 64, j0 = bj * 64;
    const float* g = g32T + (size_t)m * CC * NN;
    int tid = threadIdx.x;
    #pragma unroll
    for (int q = 0; q < 16; ++q) {
        int idx = q * 256 + tid;
        int k = idx >> 6, r = idx & 63;
        As[k][r] = g[(size_t)k * NN + i0 + r];
        Bs[k][r] = g[(size_t)k * NN + j0 + r];
    }
    __syncthreads();
    int tr = tid >> 4, tc = tid & 15;
    float acc[4][4] = {{0.f}};
    #pragma unroll
    for (int k = 0; k < CC; ++k) {
        float4 a = *((const float4*)&As[k][tr << 2]);
        float4 b = *((const float4*)&Bs[k][tc << 2]);
        acc[0][0] += a.x * b.x; acc[0][1] += a.x * b.y; acc[0][2] += a.x * b.z; acc[0][3] += a.x * b.w;
        acc[1][0] += a.y * b.x; acc[1][1] += a.y * b.y; acc[1][2] += a.y * b.z; acc[1][3] += a.y * b.w;
        acc[2][0] += a.z * b.x; acc[2][1] += a.z * b.y; acc[2][2] += a.z * b.z; acc[2][3] += a.z * b.w;
        acc[3][0] += a.w * b.x; acc[3][1] += a.w * b.y; acc[3][2] += a.w * b.z; acc[3][3] += a.w * b.w;
    }
    float* srow = sims + (size_t)m * NN * NN;
    #pragma unroll
    for (int x = 0; x < 4; ++x) {
        float4 v = make_float4(acc[x][0], acc[x][1], acc[x][2], acc[x][3]);
        *((float4*)&srow[(size_t)(i0 + (tr << 2) + x) * NN + j0 + (tc << 2)]) = v;
    }
}

// ---------------------------------------------------------------------------
// 3) f32 threshold + margin candidate capture (NO explicit top-K ordering —
//    the f64 refine pass does exact ranking anyway).
//    Binary search (20 steps, ballot-count) brackets the f32 K-th value:
//    lo <= vK < hi, hi-lo ~= 2e-6. thr = lo - 1e-5 <= vK - 1e-5.
//    Guarantee: every true f64 top-K j has s32[j] >= vK - 2*eps (eps<=4.2e-6,
//    unit-norm rows) >= thr, so cand is a provable superset of the f64 top-K.
//    Count probes are pure v_cmp + ballot (scalar popc/add) — no dependent
//    cndmask chains, no shuffles.
// ---------------------------------------------------------------------------
__global__ void __launch_bounds__(512)
k_select(const float* __restrict__ sims, int* __restrict__ cand, int* __restrict__ cntb) {
    int wave = threadIdx.x >> 6, lane = threadIdx.x & 63;
    int row = blockIdx.x * 8 + wave;    // 0..4095
    int m = row >> 11, i = row & 2047;
    int K = m ? 13 : 19;
    const float* s = sims + (size_t)m * NN * NN + (size_t)i * NN;
    float sv[32];
    #pragma unroll
    for (int q = 0; q < 8; ++q) {
        float4 v = *((const float4*)&s[q * 256 + (lane << 2)]);
        sv[q * 4 + 0] = v.x; sv[q * 4 + 1] = v.y; sv[q * 4 + 2] = v.z; sv[q * 4 + 3] = v.w;
    }
    // element r of lane: j = (r>>2)*256 + lane*4 + (r&3)
    float lo = -1.01f, hi = 1.01f;     // cosine sims live in [-1,1]
    for (int it = 0; it < 20; ++it) {
        float t = 0.5f * (lo + hi);
        int cnt = 0;
        #pragma unroll
        for (int r = 0; r < 32; ++r)
            cnt += __popcll(__ballot(sv[r] >= t));
        if (cnt >= K) lo = t; else hi = t;   // wave-uniform branch
    }
    float thr = lo - 1e-5f;
    unsigned long long ltmask = (lane == 0) ? 0ull : ((~0ull) >> (64 - lane));
    int base = 0;
    int* crow = cand + (size_t)row * CANDCAP;
    #pragma unroll
    for (int r = 0; r < 32; ++r) {
        int j = ((r >> 2) << 8) + (lane << 2) + (r & 3);
        bool p = sv[r] >= thr;
        unsigned long long mk = __ballot(p);
        int ofs = base + __popcll(mk & ltmask);
        if (p && ofs < CANDCAP) crow[ofs] = j;
        base += __popcll(mk);
    }
    if (lane == 0) cntb[row] = (base < CANDCAP) ? base : CANDCAP;
}

// ---------------------------------------------------------------------------
// 4) exact f64 refine: per row, f64 dots for candidates, exact rank placement
// ---------------------------------------------------------------------------
__global__ void k_refine(const double* __restrict__ gR64,
                         const int* __restrict__ cand, const int* __restrict__ cntb,
                         int* __restrict__ knn1, int* __restrict__ knn2) {
    __shared__ double dots[CANDCAP];
    int row = blockIdx.x, lane = threadIdx.x;   // 64 threads
    int m = row >> 11, i = row & 2047;
    int K = m ? 13 : 19;
    int cnt = cntb[row]; if (cnt > CANDCAP) cnt = CANDCAP;
    const double* gm = gR64 + (size_t)m * NN * CC;
    const int* crow = cand + (size_t)row * CANDCAP;
    double qc = gm[(size_t)i * CC + lane];
    for (int t = 0; t < cnt; ++t) {
        int j = crow[t];
        double p = qc * gm[(size_t)j * CC + lane];
        #pragma unroll
        for (int d = 32; d >= 1; d >>= 1) p += __shfl_xor(p, d);
        if (lane == 0) dots[t] = p;
    }
    __syncthreads();
    int* knn = m ? knn2 : knn1;
    if (lane < cnt) {
        double vt = dots[lane]; int jt = crow[lane];
        int rank = 0;
        for (int s = 0; s < cnt; ++s) {
            double vs = dots[s]; int js = crow[s];
            if (vs > vt || (vs == vt && js < jt)) ++rank;
        }
        if (rank < K) knn[(size_t)i * K + rank] = jt;
    }
}

// ---------------------------------------------------------------------------
// 5) node degrees DV. init to 1 (inter edge), scatter-count.
// ---------------------------------------------------------------------------
__global__ void k_dv_init(int* __restrict__ DV) {
    int v = blockIdx.x * blockDim.x + threadIdx.x;
    if (v < TWO_N) DV[v] = 1;
}

__global__ void k_dv_count(const int* __restrict__ knn1, const int* __restrict__ knn2,
                           int* __restrict__ DV) {
    int id = blockIdx.x * blockDim.x + threadIdx.x;
    if (id < NN * 19) {
        int t = id % 19;
        int v = knn1[id];
        atomicAdd(&DV[v], (t < 7) ? 2 : 1);      // in both k=6 and k=18 edges
    } else if (id < NN * 19 + NN * 13) {
        int id2 = id - NN * 19;
        int t = id2 % 13;
        int v = NN + knn2[id2];
        atomicAdd(&DV[v], (t < 5) ? 2 : 1);
    }
}

// ---------------------------------------------------------------------------
// 6) exclusive scan of DV -> CSR offsets; cursor copy; dvis = 1/sqrt(DV)
// ---------------------------------------------------------------------------
__global__ void k_scan(const int* __restrict__ DV, int* __restrict__ offs,
                       int* __restrict__ cursor, double* __restrict__ dvis) {
    int lane = threadIdx.x;      // 64
    int base = lane * 64;
    int s = 0;
    for (int q = 0; q < 64; ++q) s += DV[base + q];
    int x = s;
    for (int d = 1; d < 64; d <<= 1) {
        int y = __shfl_up(x, d);
        if (lane >= d) x += y;
    }
    int run = x - s;             // exclusive prefix of lane chunk
    for (int q = 0; q < 64; ++q) {
        int v = base + q;
        offs[v] = run; cursor[v] = run;
        dvis[v] = 1.0 / sqrt((double)DV[v]);
        run += DV[v];
    }
    if (lane == 63) offs[TWO_N] = run;   // == NNZ
}

// ---------------------------------------------------------------------------
// 7) fill CSR transpose: node v -> list of edge ids containing v
// ---------------------------------------------------------------------------
__global__ void k_fill(const int* __restrict__ knn1, const int* __restrict__ knn2,
                       int* __restrict__ cursor, int* __restrict__ entries) {
    int id = blockIdx.x * blockDim.x + threadIdx.x;
    const int M1 = NN * 19, M2 = NN * 13;
    if (id < M1) {
        int i = id / 19, t = id % 19;
        int v = knn1[id];
        int p = atomicAdd(&cursor[v], 1); entries[p] = NN + i;       // k=18 edge
        if (t < 7) { int p2 = atomicAdd(&cursor[v], 1); entries[p2] = i; }
    } else if (id < M1 + M2) {
        int id2 = id - M1;
        int i = id2 / 13, t = id2 % 13;
        int v = NN + knn2[id2];
        int p = atomicAdd(&cursor[v], 1); entries[p] = 3 * NN + i;   // k=12 edge
        if (t < 5) { int p2 = atomicAdd(&cursor[v], 1); entries[p2] = 2 * NN + i; }
    } else if (id < M1 + M2 + TWO_N) {
        int v = id - (M1 + M2);
        int i = (v < NN) ? v : (v - NN);
        int p = atomicAdd(&cursor[v], 1); entries[p] = 4 * NN + i;   // inter edge
    }
}

// ---------------------------------------------------------------------------
// 8) y = x @ W1^T  (Fin=64, f64 accum, f32 store). 8 rows/block, 128 threads.
//    W1 staged ROW-MAJOR with +1 pad: WT[o*65+c] (conflict-free, 2-way max).
// ---------------------------------------------------------------------------
__global__ void k_gemm1(const float* __restrict__ f1, const float* __restrict__ f2,
                        const float* __restrict__ W1, float* __restrict__ y) {
    __shared__ float WT[HD * 65];     // 33.3 KB, row-major padded
    __shared__ double xr[8][CC];      // 4 KB
    int tid = threadIdx.x;
    for (int idx = tid * 4; idx < HD * CC; idx += 128 * 4) {
        float4 w4 = *((const float4*)&W1[idx]);   // coalesced 16B
        int o = idx >> 6, c = idx & 63;
        WT[o * 65 + c + 0] = w4.x;
        WT[o * 65 + c + 1] = w4.y;
        WT[o * 65 + c + 2] = w4.z;
        WT[o * 65 + c + 3] = w4.w;
    }
    int g0 = blockIdx.x * 8;          // global row = b*4096+v
    for (int idx = tid; idx < 8 * CC; idx += 128) {
        int r = idx >> 6, c = idx & 63;
        int rv = g0 + r, b = rv >> 12, v = rv & 4095;
        float val = (v < NN) ? f1[((size_t)(b * NN) + v) * CC + c]
                             : f2[((size_t)(b * NN) + (v - NN)) * CC + c];
        xr[r][c] = (double)val;
    }
    __syncthreads();
    int o = tid;
    double acc[8] = {0, 0, 0, 0, 0, 0, 0, 0};
    #pragma unroll
    for (int c = 0; c < CC; ++c) {
        double w = (double)WT[o * 65 + c];
        #pragma unroll
        for (int r = 0; r < 8; ++r) acc[r] += w * xr[r][c];
    }
    for (int r = 0; r < 8; ++r) y[(size_t)(g0 + r) * HD + o] = (float)acc[r];
}

// ---------------------------------------------------------------------------
// 9) y = z @ W2^T (Fin=128, f32 in, f64 accum, f32 store).
//    W2 staged per-64-col half, row-major padded: WTh[o*65+cl]. Conflict-free.
// ---------------------------------------------------------------------------
__global__ void k_gemm2(const float* __restrict__ z, const float* __restrict__ W2,
                        float* __restrict__ y) {
    __shared__ float WTh[HD * 65];    // 33.3 KB, half of W2 (64 cols), padded
    __shared__ double xr[8][HD];      // 8 KB
    int tid = threadIdx.x;
    int g0 = blockIdx.x * 8;
    for (int idx = tid; idx < 8 * HD; idx += 128) {
        int r = idx >> 7, c = idx & 127;
        xr[r][c] = (double)z[(size_t)(g0 + r) * HD + c];
    }
    int o = tid;
    double acc[8] = {0, 0, 0, 0, 0, 0, 0, 0};
    for (int h = 0; h < 2; ++h) {
        __syncthreads();
        for (int idx = tid * 4; idx < HD * 64; idx += 128 * 4) {
            int oo = idx >> 6, cl = idx & 63;
            float4 w4 = *((const float4*)&W2[(size_t)oo * HD + h * 64 + cl]);
            WTh[oo * 65 + cl + 0] = w4.x;
            WTh[oo * 65 + cl + 1] = w4.y;
            WTh[oo * 65 + cl + 2] = w4.z;
            WTh[oo * 65 + cl + 3] = w4.w;
        }
        __syncthreads();
        #pragma unroll
        for (int cl = 0; cl < 64; ++cl) {
            double w = (double)WTh[o * 65 + cl];
            int c = h * 64 + cl;
            #pragma unroll
            for (int r = 0; r < 8; ++r) acc[r] += w * xr[r][c];
        }
    }
    for (int r = 0; r < 8; ++r) y[(size_t)(g0 + r) * HD + o] = (float)acc[r];
}

// ---------------------------------------------------------------------------
// 10) edge stage: u[b,e,f] = DE^-2 * sum_{v in e} y[b,v,f] * dvis[v]
// ---------------------------------------------------------------------------
__global__ void k_edge(const float* __restrict__ y, const double* __restrict__ dvis,
                       const int* __restrict__ knn1, const int* __restrict__ knn2,
                       float* __restrict__ u) {
    __shared__ int mem[19];
    __shared__ double wv[19];
    int e = blockIdx.x, f = threadIdx.x;
    int cnt;
    if      (e < NN)     cnt = 7;
    else if (e < 2 * NN) cnt = 19;
    else if (e < 3 * NN) cnt = 5;
    else if (e < 4 * NN) cnt = 13;
    else                 cnt = 2;
    if (f < cnt) {
        int v;
        if      (e < NN)     v = knn1[(size_t)e * 19 + f];
        else if (e < 2 * NN) v = knn1[(size_t)(e - NN) * 19 + f];
        else if (e < 3 * NN) v = NN + knn2[(size_t)(e - 2 * NN) * 13 + f];
        else if (e < 4 * NN) v = NN + knn2[(size_t)(e - 3 * NN) * 13 + f];
        else                 v = (f == 0) ? (e - 4 * NN) : (e - 4 * NN + NN);
        mem[f] = v;
        wv[f] = dvis[v];
    }
    __syncthreads();
    double acc[BB] = {0, 0, 0, 0};
    for (int t = 0; t < cnt; ++t) {
        double w = wv[t];
        size_t base = (size_t)mem[t] * HD + f;
        #pragma unroll
        for (int b = 0; b < BB; ++b)
            acc[b] += (double)y[(size_t)b * TWO_N * HD + base] * w;
    }
    double inv = 1.0 / (double)(cnt * cnt);
    #pragma unroll
    for (int b = 0; b < BB; ++b)
        u[((size_t)b * NE + e) * HD + f] = (float)(acc[b] * inv);
}

// ---------------------------------------------------------------------------
// 11) node stage: z[b,v,f] = relu( dvis[v] * sum_{e in CSR[v]} u[b,e,f] )
// ---------------------------------------------------------------------------
__global__ void k_node(const float* __restrict__ u, const double* __restrict__ dvis,
                       const int* __restrict__ offs, const int* __restrict__ entries,
                       float* __restrict__ zbuf, float* __restrict__ outp, int layer) {
    int v = blockIdx.x, f = threadIdx.x;
    int s = offs[v], e_end = offs[v + 1];
    double acc[BB] = {0, 0, 0, 0};
    for (int p = s; p < e_end; ++p) {
        int e = entries[p];               // broadcast load
        size_t base = (size_t)e * HD + f;
        #pragma unroll
        for (int b = 0; b < BB; ++b)
            acc[b] += (double)u[(size_t)b * NE * HD + base];
    }
    double dv = dvis[v];
    #pragma unroll
    for (int b = 0; b < BB; ++b) {
        double res = dv * acc[b];
        if (res < 0.0) res = 0.0;
        if (layer == 0) {
            zbuf[((size_t)b * TWO_N + v) * HD + f] = (float)res;
        } else {
            size_t o;
            if (v < NN) o = ((size_t)(b * NN + v)) * HD + f;
            else        o = (size_t)BB * NN * HD + ((size_t)(b * NN + (v - NN))) * HD + f;
            outp[o] = (float)res;
        }
    }
}

// ---------------------------------------------------------------------------
extern "C" void kernel_launch(void* const* d_in, const int* in_sizes, int n_in,
                              void* d_out, int out_size, void* d_ws, size_t ws_size,
                              hipStream_t stream) {
    const float* f1 = (const float*)d_in[0];
    const float* f2 = (const float*)d_in[1];
    const float* W1 = (const float*)d_in[2];
    const float* W2 = (const float*)d_in[3];
    float* out = (float*)d_out;

    // bump allocator over d_ws (~72 MB)
    char* ws = (char*)d_ws;
    size_t off = 0;
    auto alloc = [&](size_t bytes) -> void* {
        void* p = ws + off;
        off = (off + bytes + 255) & ~(size_t)255;
        return p;
    };
    float*  g32T    = (float*)alloc((size_t)2 * CC * NN * 4);         // 1 MB
    double* gR64    = (double*)alloc((size_t)2 * NN * CC * 8);        // 2 MB
    float*  sims    = (float*)alloc((size_t)2 * NN * NN * 4);         // 32 MB
    float*  ybuf    = (float*)alloc((size_t)BB * TWO_N * HD * 4);     // 8 MB
    float*  zbuf    = (float*)alloc((size_t)BB * TWO_N * HD * 4);     // 8 MB
    float*  ubuf    = (float*)alloc((size_t)BB * NE * HD * 4);        // 20 MB
    double* dvis    = (double*)alloc((size_t)TWO_N * 8);
    int*    knn1    = (int*)alloc((size_t)NN * 19 * 4);
    int*    knn2    = (int*)alloc((size_t)NN * 13 * 4);
    int*    DV      = (int*)alloc((size_t)TWO_N * 4);
    int*    offs    = (int*)alloc((size_t)(TWO_N + 1) * 4);
    int*    cursor  = (int*)alloc((size_t)TWO_N * 4);
    int*    entries = (int*)alloc((size_t)NNZ * 4);
    int*    cand    = (int*)alloc((size_t)TWO_N * CANDCAP * 4);       // 512 KB
    int*    cntb    = (int*)alloc((size_t)TWO_N * 4);

    // graph construction: f32 sims + threshold-filter + provably-exact f64 refine
    k_mean_norm<<<dim3(NN, 2), 64, 0, stream>>>(f1, f2, g32T, gR64);
    k_sims<<<dim3(32 * 32, 2), 256, 0, stream>>>(g32T, sims);
    k_select<<<TWO_N / 8, 512, 0, stream>>>(sims, cand, cntb);
    k_refine<<<TWO_N, 64, 0, stream>>>(gR64, cand, cntb, knn1, knn2);
    k_dv_init<<<(TWO_N + 255) / 256, 256, 0, stream>>>(DV);
    k_dv_count<<<(NN * 19 + NN * 13 + 255) / 256, 256, 0, stream>>>(knn1, knn2, DV);
    k_scan<<<1, 64, 0, stream>>>(DV, offs, cursor, dvis);
    k_fill<<<(NN * 19 + NN * 13 + TWO_N + 255) / 256, 256, 0, stream>>>(knn1, knn2, cursor, entries);

    // layer 1
    k_gemm1<<<(BB * TWO_N) / 8, 128, 0, stream>>>(f1, f2, W1, ybuf);
    k_edge<<<NE, 128, 0, stream>>>(ybuf, dvis, knn1, knn2, ubuf);
    k_node<<<TWO_N, 128, 0, stream>>>(ubuf, dvis, offs, entries, zbuf, nullptr, 0);

    // layer 2
    k_gemm2<<<(BB * TWO_N) / 8, 128, 0, stream>>>(zbuf, W2, ybuf);
    k_edge<<<NE, 128, 0, stream>>>(ybuf, dvis, knn1, knn2, ubuf);
    k_node<<<TWO_N, 128, 0, stream>>>(ubuf, dvis, offs, entries, nullptr, out, 1);
}

// Round 8
// 261.329 us; speedup vs baseline: 4.4369x; 1.0977x over previous
//
#include <hip/hip_runtime.h>
#include <math.h>

// Problem constants
#define NN 2048      // nodes per modality
#define TWO_N 4096   // total nodes
#define NE 10240     // total hyperedges (5N)
#define BB 4         // batch
#define CC 64        // input feature dim
#define HD 128       // hidden dim
#define NNZ 94208    // 2048*(7+19) + 2048*(5+13) + 2*2048
#define CANDCAP 32   // max top-k candidates per row after f32 margin filter
#define KC 32        // gemm K-chunk

// ---------------------------------------------------------------------------
// 1) batch-mean + L2-normalize.
// ---------------------------------------------------------------------------
__global__ void k_mean_norm(const float* __restrict__ f1, const float* __restrict__ f2,
                            float* __restrict__ g32T, double* __restrict__ gR64) {
    int n = blockIdx.x;           // node
    int m = blockIdx.y;           // modality
    int c = threadIdx.x;          // 64 threads = 1 wave
    const float* f = m ? f2 : f1;
    double s = 0.0;
    for (int b = 0; b < BB; ++b) s += (double)f[((size_t)(b * NN) + n) * CC + c];
    double mean = s * 0.25;
    double sq = mean * mean;
    for (int d = 32; d >= 1; d >>= 1) sq += __shfl_xor(sq, d);
    double norm = sqrt(sq);
    if (norm < 1e-12) norm = 1e-12;
    double g = mean / norm;
    g32T[((size_t)m * CC + c) * NN + n] = (float)g;
    gR64[((size_t)m * NN + n) * CC + c] = g;
}

// ---------------------------------------------------------------------------
// 2) f32 sims GEMM: sims[m] = G32 * G32^T  (2048x2048, K=64).
// ---------------------------------------------------------------------------
__global__ void __launch_bounds__(256)
k_sims(const float* __restrict__ g32T, float* __restrict__ sims) {
    __shared__ float As[CC][64];   // As[k][r], 16 KB
    __shared__ float Bs[CC][64];   // Bs[k][j], 16 KB
    int m  = blockIdx.y;
    int bi = blockIdx.x >> 5, bj = blockIdx.x & 31;
    int i0 = bi * 64, j0 = bj * 64;
    const float* g = g32T + (size_t)m * CC * NN;
    int tid = threadIdx.x;
    #pragma unroll
    for (int q = 0; q < 16; ++q) {
        int idx = q * 256 + tid;
        int k = idx >> 6, r = idx & 63;
        As[k][r] = g[(size_t)k * NN + i0 + r];
        Bs[k][r] = g[(size_t)k * NN + j0 + r];
    }
    __syncthreads();
    int tr = tid >> 4, tc = tid & 15;
    float acc[4][4] = {{0.f}};
    #pragma unroll
    for (int k = 0; k < CC; ++k) {
        float4 a = *((const float4*)&As[k][tr << 2]);
        float4 b = *((const float4*)&Bs[k][tc << 2]);
        acc[0][0] += a.x * b.x; acc[0][1] += a.x * b.y; acc[0][2] += a.x * b.z; acc[0][3] += a.x * b.w;
        acc[1][0] += a.y * b.x; acc[1][1] += a.y * b.y; acc[1][2] += a.y * b.z; acc[1][3] += a.y * b.w;
        acc[2][0] += a.z * b.x; acc[2][1] += a.z * b.y; acc[2][2] += a.z * b.z; acc[2][3] += a.z * b.w;
        acc[3][0] += a.w * b.x; acc[3][1] += a.w * b.y; acc[3][2] += a.w * b.z; acc[3][3] += a.w * b.w;
    }
    float* srow = sims + (size_t)m * NN * NN;
    #pragma unroll
    for (int x = 0; x < 4; ++x) {
        float4 v = make_float4(acc[x][0], acc[x][1], acc[x][2], acc[x][3]);
        *((float4*)&srow[(size_t)(i0 + (tr << 2) + x) * NN + j0 + (tc << 2)]) = v;
    }
}

// ---------------------------------------------------------------------------
// 3) f32 threshold + margin candidate capture (binary-search ballot count).
//    thr = lo - 1e-5 <= vK_f32 - 2*eps  =>  cand superset of true f64 top-K.
// ---------------------------------------------------------------------------
__global__ void __launch_bounds__(512)
k_select(const float* __restrict__ sims, int* __restrict__ cand, int* __restrict__ cntb) {
    int wave = threadIdx.x >> 6, lane = threadIdx.x & 63;
    int row = blockIdx.x * 8 + wave;    // 0..4095
    int m = row >> 11, i = row & 2047;
    int K = m ? 13 : 19;
    const float* s = sims + (size_t)m * NN * NN + (size_t)i * NN;
    float sv[32];
    #pragma unroll
    for (int q = 0; q < 8; ++q) {
        float4 v = *((const float4*)&s[q * 256 + (lane << 2)]);
        sv[q * 4 + 0] = v.x; sv[q * 4 + 1] = v.y; sv[q * 4 + 2] = v.z; sv[q * 4 + 3] = v.w;
    }
    float lo = -1.01f, hi = 1.01f;     // cosine sims live in [-1,1]
    for (int it = 0; it < 20; ++it) {
        float t = 0.5f * (lo + hi);
        int cnt = 0;
        #pragma unroll
        for (int r = 0; r < 32; ++r)
            cnt += __popcll(__ballot(sv[r] >= t));
        if (cnt >= K) lo = t; else hi = t;   // wave-uniform branch
    }
    float thr = lo - 1e-5f;
    unsigned long long ltmask = (lane == 0) ? 0ull : ((~0ull) >> (64 - lane));
    int base = 0;
    int* crow = cand + (size_t)row * CANDCAP;
    #pragma unroll
    for (int r = 0; r < 32; ++r) {
        int j = ((r >> 2) << 8) + (lane << 2) + (r & 3);
        bool p = sv[r] >= thr;
        unsigned long long mk = __ballot(p);
        int ofs = base + __popcll(mk & ltmask);
        if (p && ofs < CANDCAP) crow[ofs] = j;
        base += __popcll(mk);
    }
    if (lane == 0) cntb[row] = (base < CANDCAP) ? base : CANDCAP;
}

// ---------------------------------------------------------------------------
// 4) exact f64 refine: per row, f64 dots for candidates, exact rank placement.
//    cnt >= K always (>=K elements satisfy s >= thr), ranks 0..cnt-1 are
//    distinct => knn rows are always fully written.
// ---------------------------------------------------------------------------
__global__ void k_refine(const double* __restrict__ gR64,
                         const int* __restrict__ cand, const int* __restrict__ cntb,
                         int* __restrict__ knn1, int* __restrict__ knn2) {
    __shared__ double dots[CANDCAP];
    int row = blockIdx.x, lane = threadIdx.x;   // 64 threads
    int m = row >> 11, i = row & 2047;
    int K = m ? 13 : 19;
    int cnt = cntb[row]; if (cnt > CANDCAP) cnt = CANDCAP;
    const double* gm = gR64 + (size_t)m * NN * CC;
    const int* crow = cand + (size_t)row * CANDCAP;
    double qc = gm[(size_t)i * CC + lane];
    for (int t = 0; t < cnt; ++t) {
        int j = crow[t];
        double p = qc * gm[(size_t)j * CC + lane];
        #pragma unroll
        for (int d = 32; d >= 1; d >>= 1) p += __shfl_xor(p, d);
        if (lane == 0) dots[t] = p;
    }
    __syncthreads();
    int* knn = m ? knn2 : knn1;
    if (lane < cnt) {
        double vt = dots[lane]; int jt = crow[lane];
        int rank = 0;
        for (int s = 0; s < cnt; ++s) {
            double vs = dots[s]; int js = crow[s];
            if (vs > vt || (vs == vt && js < jt)) ++rank;
        }
        if (rank < K) knn[(size_t)i * K + rank] = jt;
    }
}

// ---------------------------------------------------------------------------
// 5) node degrees DV. init to 1 (inter edge), scatter-count.
// ---------------------------------------------------------------------------
__global__ void k_dv_init(int* __restrict__ DV) {
    int v = blockIdx.x * blockDim.x + threadIdx.x;
    if (v < TWO_N) DV[v] = 1;
}

__global__ void k_dv_count(const int* __restrict__ knn1, const int* __restrict__ knn2,
                           int* __restrict__ DV) {
    int id = blockIdx.x * blockDim.x + threadIdx.x;
    if (id < NN * 19) {
        int t = id % 19;
        int v = knn1[id];
        atomicAdd(&DV[v], (t < 7) ? 2 : 1);      // in both k=6 and k=18 edges
    } else if (id < NN * 19 + NN * 13) {
        int id2 = id - NN * 19;
        int t = id2 % 13;
        int v = NN + knn2[id2];
        atomicAdd(&DV[v], (t < 5) ? 2 : 1);
    }
}

// ---------------------------------------------------------------------------
// 6) exclusive scan of DV -> CSR offsets; cursor copy; dvis = 1/sqrt(DV)
// ---------------------------------------------------------------------------
__global__ void k_scan(const int* __restrict__ DV, int* __restrict__ offs,
                       int* __restrict__ cursor, double* __restrict__ dvis) {
    int lane = threadIdx.x;      // 64
    int base = lane * 64;
    int s = 0;
    for (int q = 0; q < 64; ++q) s += DV[base + q];
    int x = s;
    for (int d = 1; d < 64; d <<= 1) {
        int y = __shfl_up(x, d);
        if (lane >= d) x += y;
    }
    int run = x - s;             // exclusive prefix of lane chunk
    for (int q = 0; q < 64; ++q) {
        int v = base + q;
        offs[v] = run; cursor[v] = run;
        dvis[v] = 1.0 / sqrt((double)DV[v]);
        run += DV[v];
    }
    if (lane == 63) offs[TWO_N] = run;   // == NNZ
}

// ---------------------------------------------------------------------------
// 7) fill CSR transpose: node v -> list of edge ids containing v
// ---------------------------------------------------------------------------
__global__ void k_fill(const int* __restrict__ knn1, const int* __restrict__ knn2,
                       int* __restrict__ cursor, int* __restrict__ entries) {
    int id = blockIdx.x * blockDim.x + threadIdx.x;
    const int M1 = NN * 19, M2 = NN * 13;
    if (id < M1) {
        int i = id / 19, t = id % 19;
        int v = knn1[id];
        int p = atomicAdd(&cursor[v], 1); entries[p] = NN + i;       // k=18 edge
        if (t < 7) { int p2 = atomicAdd(&cursor[v], 1); entries[p2] = i; }
    } else if (id < M1 + M2) {
        int id2 = id - M1;
        int i = id2 / 13, t = id2 % 13;
        int v = NN + knn2[id2];
        int p = atomicAdd(&cursor[v], 1); entries[p] = 3 * NN + i;   // k=12 edge
        if (t < 5) { int p2 = atomicAdd(&cursor[v], 1); entries[p2] = 2 * NN + i; }
    } else if (id < M1 + M2 + TWO_N) {
        int v = id - (M1 + M2);
        int i = (v < NN) ? v : (v - NN);
        int p = atomicAdd(&cursor[v], 1); entries[p] = 4 * NN + i;   // inter edge
    }
}

// ---------------------------------------------------------------------------
// 8) y = x @ W1^T (K=64). Register-tiled f64: thread = 4 rows x 4 cols.
//    Block = 32 rows, 256 threads, K chunks of 32, k-major padded LDS tiles.
//    6 DS reads / 16 f64 FMA, conflict-free by construction.
// ---------------------------------------------------------------------------
__global__ void __launch_bounds__(256)
k_gemm1(const float* __restrict__ f1, const float* __restrict__ f2,
        const float* __restrict__ W1, float* __restrict__ y) {
    __shared__ double xT[KC][33];    // [k][row] +1 pad, 8.4 KB
    __shared__ double wT[KC][130];   // [k][col] +2 pad, 33.3 KB
    int tid = threadIdx.x;
    int g0 = blockIdx.x * 32;        // 512 blocks; blocks never straddle modality
    int b = g0 >> 12, v0 = g0 & 4095;
    const float* src = (v0 < NN) ? (f1 + ((size_t)(b * NN) + v0) * CC)
                                 : (f2 + ((size_t)(b * NN) + (v0 - NN)) * CC);
    int tr = tid >> 5, tc = tid & 31;
    int r0 = tr * 4;
    double acc[4][4] = {{0.0}};
    for (int kc = 0; kc < CC / KC; ++kc) {
        int k0 = kc * KC;
        __syncthreads();
        #pragma unroll
        for (int q = 0; q < 4; ++q) {          // stage x: 32 rows x 32 k
            int idx = q * 256 + tid;
            int row = idx >> 5, k = idx & 31;
            xT[k][row] = (double)src[(size_t)row * CC + k0 + k];
        }
        #pragma unroll
        for (int q = 0; q < 16; ++q) {         // stage W1: 128 cols x 32 k
            int idx = q * 256 + tid;
            int c = idx >> 5, k = idx & 31;
            wT[k][c] = (double)W1[(size_t)c * CC + k0 + k];
        }
        __syncthreads();
        #pragma unroll
        for (int k = 0; k < KC; ++k) {
            double xr[4], wr[4];
            #pragma unroll
            for (int i = 0; i < 4; ++i) xr[i] = xT[k][r0 + i];
            #pragma unroll
            for (int j = 0; j < 4; ++j) wr[j] = wT[k][tc + 32 * j];
            #pragma unroll
            for (int i = 0; i < 4; ++i)
                #pragma unroll
                for (int j = 0; j < 4; ++j)
                    acc[i][j] += xr[i] * wr[j];
        }
    }
    #pragma unroll
    for (int i = 0; i < 4; ++i)
        #pragma unroll
        for (int j = 0; j < 4; ++j)
            y[(size_t)(g0 + r0 + i) * HD + tc + 32 * j] = (float)acc[i][j];
}

// ---------------------------------------------------------------------------
// 9) y = z @ W2^T (K=128). Same register-tiled structure.
// ---------------------------------------------------------------------------
__global__ void __launch_bounds__(256)
k_gemm2(const float* __restrict__ z, const float* __restrict__ W2,
        float* __restrict__ y) {
    __shared__ double zT[KC][33];
    __shared__ double wT[KC][130];
    int tid = threadIdx.x;
    int g0 = blockIdx.x * 32;        // 512 blocks
    int tr = tid >> 5, tc = tid & 31;
    int r0 = tr * 4;
    double acc[4][4] = {{0.0}};
    for (int kc = 0; kc < HD / KC; ++kc) {
        int k0 = kc * KC;
        __syncthreads();
        #pragma unroll
        for (int q = 0; q < 4; ++q) {          // stage z: 32 rows x 32 k
            int idx = q * 256 + tid;
            int row = idx >> 5, k = idx & 31;
            zT[k][row] = (double)z[(size_t)(g0 + row) * HD + k0 + k];
        }
        #pragma unroll
        for (int q = 0; q < 16; ++q) {         // stage W2: 128 cols x 32 k
            int idx = q * 256 + tid;
            int c = idx >> 5, k = idx & 31;
            wT[k][c] = (double)W2[(size_t)c * HD + k0 + k];
        }
        __syncthreads();
        #pragma unroll
        for (int k = 0; k < KC; ++k) {
            double zr[4], wr[4];
            #pragma unroll
            for (int i = 0; i < 4; ++i) zr[i] = zT[k][r0 + i];
            #pragma unroll
            for (int j = 0; j < 4; ++j) wr[j] = wT[k][tc + 32 * j];
            #pragma unroll
            for (int i = 0; i < 4; ++i)
                #pragma unroll
                for (int j = 0; j < 4; ++j)
                    acc[i][j] += zr[i] * wr[j];
        }
    }
    #pragma unroll
    for (int i = 0; i < 4; ++i)
        #pragma unroll
        for (int j = 0; j < 4; ++j)
            y[(size_t)(g0 + r0 + i) * HD + tc + 32 * j] = (float)acc[i][j];
}

// ---------------------------------------------------------------------------
// 10) edge stage: u[b,e,f] = DE^-2 * sum_{v in e} y[b,v,f] * dvis[v]
// ---------------------------------------------------------------------------
__global__ void k_edge(const float* __restrict__ y, const double* __restrict__ dvis,
                       const int* __restrict__ knn1, const int* __restrict__ knn2,
                       float* __restrict__ u) {
    __shared__ int mem[19];
    __shared__ double wv[19];
    int e = blockIdx.x, f = threadIdx.x;
    int cnt;
    if      (e < NN)     cnt = 7;
    else if (e < 2 * NN) cnt = 19;
    else if (e < 3 * NN) cnt = 5;
    else if (e < 4 * NN) cnt = 13;
    else                 cnt = 2;
    if (f < cnt) {
        int v;
        if      (e < NN)     v = knn1[(size_t)e * 19 + f];
        else if (e < 2 * NN) v = knn1[(size_t)(e - NN) * 19 + f];
        else if (e < 3 * NN) v = NN + knn2[(size_t)(e - 2 * NN) * 13 + f];
        else if (e < 4 * NN) v = NN + knn2[(size_t)(e - 3 * NN) * 13 + f];
        else                 v = (f == 0) ? (e - 4 * NN) : (e - 4 * NN + NN);
        mem[f] = v;
        wv[f] = dvis[v];
    }
    __syncthreads();
    double acc[BB] = {0, 0, 0, 0};
    for (int t = 0; t < cnt; ++t) {
        double w = wv[t];
        size_t base = (size_t)mem[t] * HD + f;
        #pragma unroll
        for (int b = 0; b < BB; ++b)
            acc[b] += (double)y[(size_t)b * TWO_N * HD + base] * w;
    }
    double inv = 1.0 / (double)(cnt * cnt);
    #pragma unroll
    for (int b = 0; b < BB; ++b)
        u[((size_t)b * NE + e) * HD + f] = (float)(acc[b] * inv);
}

// ---------------------------------------------------------------------------
// 11) node stage: z[b,v,f] = relu( dvis[v] * sum_{e in CSR[v]} u[b,e,f] )
// ---------------------------------------------------------------------------
__global__ void k_node(const float* __restrict__ u, const double* __restrict__ dvis,
                       const int* __restrict__ offs, const int* __restrict__ entries,
                       float* __restrict__ zbuf, float* __restrict__ outp, int layer) {
    int v = blockIdx.x, f = threadIdx.x;
    int s = offs[v], e_end = offs[v + 1];
    double acc[BB] = {0, 0, 0, 0};
    for (int p = s; p < e_end; ++p) {
        int e = entries[p];               // broadcast load
        size_t base = (size_t)e * HD + f;
        #pragma unroll
        for (int b = 0; b < BB; ++b)
            acc[b] += (double)u[(size_t)b * NE * HD + base];
    }
    double dv = dvis[v];
    #pragma unroll
    for (int b = 0; b < BB; ++b) {
        double res = dv * acc[b];
        if (res < 0.0) res = 0.0;
        if (layer == 0) {
            zbuf[((size_t)b * TWO_N + v) * HD + f] = (float)res;
        } else {
            size_t o;
            if (v < NN) o = ((size_t)(b * NN + v)) * HD + f;
            else        o = (size_t)BB * NN * HD + ((size_t)(b * NN + (v - NN))) * HD + f;
            outp[o] = (float)res;
        }
    }
}

// ---------------------------------------------------------------------------
extern "C" void kernel_launch(void* const* d_in, const int* in_sizes, int n_in,
                              void* d_out, int out_size, void* d_ws, size_t ws_size,
                              hipStream_t stream) {
    const float* f1 = (const float*)d_in[0];
    const float* f2 = (const float*)d_in[1];
    const float* W1 = (const float*)d_in[2];
    const float* W2 = (const float*)d_in[3];
    float* out = (float*)d_out;

    // bump allocator over d_ws (~72 MB)
    char* ws = (char*)d_ws;
    size_t off = 0;
    auto alloc = [&](size_t bytes) -> void* {
        void* p = ws + off;
        off = (off + bytes + 255) & ~(size_t)255;
        return p;
    };
    float*  g32T    = (float*)alloc((size_t)2 * CC * NN * 4);         // 1 MB
    double* gR64    = (double*)alloc((size_t)2 * NN * CC * 8);        // 2 MB
    float*  sims    = (float*)alloc((size_t)2 * NN * NN * 4);         // 32 MB
    float*  ybuf    = (float*)alloc((size_t)BB * TWO_N * HD * 4);     // 8 MB
    float*  zbuf    = (float*)alloc((size_t)BB * TWO_N * HD * 4);     // 8 MB
    float*  ubuf    = (float*)alloc((size_t)BB * NE * HD * 4);        // 20 MB
    double* dvis    = (double*)alloc((size_t)TWO_N * 8);
    int*    knn1    = (int*)alloc((size_t)NN * 19 * 4);
    int*    knn2    = (int*)alloc((size_t)NN * 13 * 4);
    int*    DV      = (int*)alloc((size_t)TWO_N * 4);
    int*    offs    = (int*)alloc((size_t)(TWO_N + 1) * 4);
    int*    cursor  = (int*)alloc((size_t)TWO_N * 4);
    int*    entries = (int*)alloc((size_t)NNZ * 4);
    int*    cand    = (int*)alloc((size_t)TWO_N * CANDCAP * 4);       // 512 KB
    int*    cntb    = (int*)alloc((size_t)TWO_N * 4);

    // graph construction: f32 sims + threshold-filter + provably-exact f64 refine
    k_mean_norm<<<dim3(NN, 2), 64, 0, stream>>>(f1, f2, g32T, gR64);
    k_sims<<<dim3(32 * 32, 2), 256, 0, stream>>>(g32T, sims);
    k_select<<<TWO_N / 8, 512, 0, stream>>>(sims, cand, cntb);
    k_refine<<<TWO_N, 64, 0, stream>>>(gR64, cand, cntb, knn1, knn2);
    k_dv_init<<<(TWO_N + 255) / 256, 256, 0, stream>>>(DV);
    k_dv_count<<<(NN * 19 + NN * 13 + 255) / 256, 256, 0, stream>>>(knn1, knn2, DV);
    k_scan<<<1, 64, 0, stream>>>(DV, offs, cursor, dvis);
    k_fill<<<(NN * 19 + NN * 13 + TWO_N + 255) / 256, 256, 0, stream>>>(knn1, knn2, cursor, entries);

    // layer 1
    k_gemm1<<<(BB * TWO_N) / 32, 256, 0, stream>>>(f1, f2, W1, ybuf);
    k_edge<<<NE, 128, 0, stream>>>(ybuf, dvis, knn1, knn2, ubuf);
    k_node<<<TWO_N, 128, 0, stream>>>(ubuf, dvis, offs, entries, zbuf, nullptr, 0);

    // layer 2
    k_gemm2<<<(BB * TWO_N) / 32, 256, 0, stream>>>(zbuf, W2, ybuf);
    k_edge<<<NE, 128, 0, stream>>>(ybuf, dvis, knn1, knn2, ubuf);
    k_node<<<TWO_N, 128, 0, stream>>>(ubuf, dvis, offs, entries, nullptr, out, 1);
}

// Round 9
// 254.602 us; speedup vs baseline: 4.5542x; 1.0264x over previous
//
#include <hip/hip_runtime.h>
#include <math.h>

// Problem constants
#define NN 2048      // nodes per modality
#define TWO_N 4096   // total nodes
#define NE 10240     // total hyperedges (5N)
#define BB 4         // batch
#define CC 64        // input feature dim
#define HD 128       // hidden dim
#define NNZ 94208    // 2048*(7+19) + 2048*(5+13) + 2*2048
#define CANDCAP 32   // max top-k candidates per row after f32 margin filter
#define KC 32        // gemm K-chunk

// ---------------------------------------------------------------------------
// 1) batch-mean + L2-normalize.
// ---------------------------------------------------------------------------
__global__ void k_mean_norm(const float* __restrict__ f1, const float* __restrict__ f2,
                            float* __restrict__ g32T, double* __restrict__ gR64) {
    int n = blockIdx.x;           // node
    int m = blockIdx.y;           // modality
    int c = threadIdx.x;          // 64 threads = 1 wave
    const float* f = m ? f2 : f1;
    double s = 0.0;
    for (int b = 0; b < BB; ++b) s += (double)f[((size_t)(b * NN) + n) * CC + c];
    double mean = s * 0.25;
    double sq = mean * mean;
    for (int d = 32; d >= 1; d >>= 1) sq += __shfl_xor(sq, d);
    double norm = sqrt(sq);
    if (norm < 1e-12) norm = 1e-12;
    double g = mean / norm;
    g32T[((size_t)m * CC + c) * NN + n] = (float)g;
    gR64[((size_t)m * NN + n) * CC + c] = g;
}

// ---------------------------------------------------------------------------
// 2) f32 sims GEMM: sims[m] = G32 * G32^T  (2048x2048, K=64).
// ---------------------------------------------------------------------------
__global__ void __launch_bounds__(256)
k_sims(const float* __restrict__ g32T, float* __restrict__ sims) {
    __shared__ float As[CC][64];   // As[k][r], 16 KB
    __shared__ float Bs[CC][64];   // Bs[k][j], 16 KB
    int m  = blockIdx.y;
    int bi = blockIdx.x >> 5, bj = blockIdx.x & 31;
    int i0 = bi * 64, j0 = bj * 64;
    const float* g = g32T + (size_t)m * CC * NN;
    int tid = threadIdx.x;
    #pragma unroll
    for (int q = 0; q < 16; ++q) {
        int idx = q * 256 + tid;
        int k = idx >> 6, r = idx & 63;
        As[k][r] = g[(size_t)k * NN + i0 + r];
        Bs[k][r] = g[(size_t)k * NN + j0 + r];
    }
    __syncthreads();
    int tr = tid >> 4, tc = tid & 15;
    float acc[4][4] = {{0.f}};
    #pragma unroll
    for (int k = 0; k < CC; ++k) {
        float4 a = *((const float4*)&As[k][tr << 2]);
        float4 b = *((const float4*)&Bs[k][tc << 2]);
        acc[0][0] += a.x * b.x; acc[0][1] += a.x * b.y; acc[0][2] += a.x * b.z; acc[0][3] += a.x * b.w;
        acc[1][0] += a.y * b.x; acc[1][1] += a.y * b.y; acc[1][2] += a.y * b.z; acc[1][3] += a.y * b.w;
        acc[2][0] += a.z * b.x; acc[2][1] += a.z * b.y; acc[2][2] += a.z * b.z; acc[2][3] += a.z * b.w;
        acc[3][0] += a.w * b.x; acc[3][1] += a.w * b.y; acc[3][2] += a.w * b.z; acc[3][3] += a.w * b.w;
    }
    float* srow = sims + (size_t)m * NN * NN;
    #pragma unroll
    for (int x = 0; x < 4; ++x) {
        float4 v = make_float4(acc[x][0], acc[x][1], acc[x][2], acc[x][3]);
        *((float4*)&srow[(size_t)(i0 + (tr << 2) + x) * NN + j0 + (tc << 2)]) = v;
    }
}

// ---------------------------------------------------------------------------
// 3) f32 threshold + margin candidate capture (binary-search ballot count).
//    Also inits DV[row]=1 (inter edge) — consumed by k_refine's atomicAdd.
// ---------------------------------------------------------------------------
__global__ void __launch_bounds__(512)
k_select(const float* __restrict__ sims, int* __restrict__ cand, int* __restrict__ cntb,
         int* __restrict__ DV) {
    int wave = threadIdx.x >> 6, lane = threadIdx.x & 63;
    int row = blockIdx.x * 8 + wave;    // 0..4095
    int m = row >> 11, i = row & 2047;
    int K = m ? 13 : 19;
    const float* s = sims + (size_t)m * NN * NN + (size_t)i * NN;
    float sv[32];
    #pragma unroll
    for (int q = 0; q < 8; ++q) {
        float4 v = *((const float4*)&s[q * 256 + (lane << 2)]);
        sv[q * 4 + 0] = v.x; sv[q * 4 + 1] = v.y; sv[q * 4 + 2] = v.z; sv[q * 4 + 3] = v.w;
    }
    float lo = -1.01f, hi = 1.01f;     // cosine sims live in [-1,1]
    for (int it = 0; it < 20; ++it) {
        float t = 0.5f * (lo + hi);
        int cnt = 0;
        #pragma unroll
        for (int r = 0; r < 32; ++r)
            cnt += __popcll(__ballot(sv[r] >= t));
        if (cnt >= K) lo = t; else hi = t;   // wave-uniform branch
    }
    float thr = lo - 1e-5f;
    unsigned long long ltmask = (lane == 0) ? 0ull : ((~0ull) >> (64 - lane));
    int base = 0;
    int* crow = cand + (size_t)row * CANDCAP;
    #pragma unroll
    for (int r = 0; r < 32; ++r) {
        int j = ((r >> 2) << 8) + (lane << 2) + (r & 3);
        bool p = sv[r] >= thr;
        unsigned long long mk = __ballot(p);
        int ofs = base + __popcll(mk & ltmask);
        if (p && ofs < CANDCAP) crow[ofs] = j;
        base += __popcll(mk);
    }
    if (lane == 0) {
        cntb[row] = (base < CANDCAP) ? base : CANDCAP;
        DV[row] = 1;                        // inter-edge contribution
    }
}

// ---------------------------------------------------------------------------
// 4) exact f64 refine + degree count. Ranks 0..cnt-1 distinct, cnt>=K =>
//    knn fully written; DV gets +2 if rank<small-k+1 (member of both edges),
//    else +1 — identical multiset to the old separate dv_count pass.
// ---------------------------------------------------------------------------
__global__ void k_refine(const double* __restrict__ gR64,
                         const int* __restrict__ cand, const int* __restrict__ cntb,
                         int* __restrict__ knn1, int* __restrict__ knn2,
                         int* __restrict__ DV) {
    __shared__ double dots[CANDCAP];
    int row = blockIdx.x, lane = threadIdx.x;   // 64 threads
    int m = row >> 11, i = row & 2047;
    int K = m ? 13 : 19;
    int cnt = cntb[row]; if (cnt > CANDCAP) cnt = CANDCAP;
    const double* gm = gR64 + (size_t)m * NN * CC;
    const int* crow = cand + (size_t)row * CANDCAP;
    double qc = gm[(size_t)i * CC + lane];
    for (int t = 0; t < cnt; ++t) {
        int j = crow[t];
        double p = qc * gm[(size_t)j * CC + lane];
        #pragma unroll
        for (int d = 32; d >= 1; d >>= 1) p += __shfl_xor(p, d);
        if (lane == 0) dots[t] = p;
    }
    __syncthreads();
    int* knn = m ? knn2 : knn1;
    if (lane < cnt) {
        double vt = dots[lane]; int jt = crow[lane];
        int rank = 0;
        for (int s = 0; s < cnt; ++s) {
            double vs = dots[s]; int js = crow[s];
            if (vs > vt || (vs == vt && js < jt)) ++rank;
        }
        if (rank < K) {
            knn[(size_t)i * K + rank] = jt;
            int w = (rank < (m ? 5 : 7)) ? 2 : 1;
            atomicAdd(&DV[m ? NN + jt : jt], w);
        }
    }
}

// ---------------------------------------------------------------------------
// 6) exclusive scan of DV -> CSR offsets; cursor copy; dvis = 1/sqrt(DV)
// ---------------------------------------------------------------------------
__global__ void k_scan(const int* __restrict__ DV, int* __restrict__ offs,
                       int* __restrict__ cursor, double* __restrict__ dvis) {
    int lane = threadIdx.x;      // 64
    int base = lane * 64;
    int s = 0;
    for (int q = 0; q < 64; ++q) s += DV[base + q];
    int x = s;
    for (int d = 1; d < 64; d <<= 1) {
        int y = __shfl_up(x, d);
        if (lane >= d) x += y;
    }
    int run = x - s;             // exclusive prefix of lane chunk
    for (int q = 0; q < 64; ++q) {
        int v = base + q;
        offs[v] = run; cursor[v] = run;
        dvis[v] = 1.0 / sqrt((double)DV[v]);
        run += DV[v];
    }
    if (lane == 63) offs[TWO_N] = run;   // == NNZ
}

// ---------------------------------------------------------------------------
// 7) fill CSR transpose: node v -> list of edge ids containing v
// ---------------------------------------------------------------------------
__global__ void k_fill(const int* __restrict__ knn1, const int* __restrict__ knn2,
                       int* __restrict__ cursor, int* __restrict__ entries) {
    int id = blockIdx.x * blockDim.x + threadIdx.x;
    const int M1 = NN * 19, M2 = NN * 13;
    if (id < M1) {
        int i = id / 19, t = id % 19;
        int v = knn1[id];
        int p = atomicAdd(&cursor[v], 1); entries[p] = NN + i;       // k=18 edge
        if (t < 7) { int p2 = atomicAdd(&cursor[v], 1); entries[p2] = i; }
    } else if (id < M1 + M2) {
        int id2 = id - M1;
        int i = id2 / 13, t = id2 % 13;
        int v = NN + knn2[id2];
        int p = atomicAdd(&cursor[v], 1); entries[p] = 3 * NN + i;   // k=12 edge
        if (t < 5) { int p2 = atomicAdd(&cursor[v], 1); entries[p2] = 2 * NN + i; }
    } else if (id < M1 + M2 + TWO_N) {
        int v = id - (M1 + M2);
        int i = (v < NN) ? v : (v - NN);
        int p = atomicAdd(&cursor[v], 1); entries[p] = 4 * NN + i;   // inter edge
    }
}

// ---------------------------------------------------------------------------
// 8) y = x @ W1^T (K=64). Register-tiled f64: thread = 4 rows x 4 cols.
// ---------------------------------------------------------------------------
__global__ void __launch_bounds__(256)
k_gemm1(const float* __restrict__ f1, const float* __restrict__ f2,
        const float* __restrict__ W1, float* __restrict__ y) {
    __shared__ double xT[KC][33];    // [k][row] +1 pad, 8.4 KB
    __shared__ double wT[KC][130];   // [k][col] +2 pad, 33.3 KB
    int tid = threadIdx.x;
    int g0 = blockIdx.x * 32;        // 512 blocks; blocks never straddle modality
    int b = g0 >> 12, v0 = g0 & 4095;
    const float* src = (v0 < NN) ? (f1 + ((size_t)(b * NN) + v0) * CC)
                                 : (f2 + ((size_t)(b * NN) + (v0 - NN)) * CC);
    int tr = tid >> 5, tc = tid & 31;
    int r0 = tr * 4;
    double acc[4][4] = {{0.0}};
    for (int kc = 0; kc < CC / KC; ++kc) {
        int k0 = kc * KC;
        __syncthreads();
        #pragma unroll
        for (int q = 0; q < 4; ++q) {          // stage x: 32 rows x 32 k
            int idx = q * 256 + tid;
            int row = idx >> 5, k = idx & 31;
            xT[k][row] = (double)src[(size_t)row * CC + k0 + k];
        }
        #pragma unroll
        for (int q = 0; q < 16; ++q) {         // stage W1: 128 cols x 32 k
            int idx = q * 256 + tid;
            int c = idx >> 5, k = idx & 31;
            wT[k][c] = (double)W1[(size_t)c * CC + k0 + k];
        }
        __syncthreads();
        #pragma unroll
        for (int k = 0; k < KC; ++k) {
            double xr[4], wr[4];
            #pragma unroll
            for (int i = 0; i < 4; ++i) xr[i] = xT[k][r0 + i];
            #pragma unroll
            for (int j = 0; j < 4; ++j) wr[j] = wT[k][tc + 32 * j];
            #pragma unroll
            for (int i = 0; i < 4; ++i)
                #pragma unroll
                for (int j = 0; j < 4; ++j)
                    acc[i][j] += xr[i] * wr[j];
        }
    }
    #pragma unroll
    for (int i = 0; i < 4; ++i)
        #pragma unroll
        for (int j = 0; j < 4; ++j)
            y[(size_t)(g0 + r0 + i) * HD + tc + 32 * j] = (float)acc[i][j];
}

// ---------------------------------------------------------------------------
// 9) y = z @ W2^T (K=128). Same register-tiled structure.
// ---------------------------------------------------------------------------
__global__ void __launch_bounds__(256)
k_gemm2(const float* __restrict__ z, const float* __restrict__ W2,
        float* __restrict__ y) {
    __shared__ double zT[KC][33];
    __shared__ double wT[KC][130];
    int tid = threadIdx.x;
    int g0 = blockIdx.x * 32;        // 512 blocks
    int tr = tid >> 5, tc = tid & 31;
    int r0 = tr * 4;
    double acc[4][4] = {{0.0}};
    for (int kc = 0; kc < HD / KC; ++kc) {
        int k0 = kc * KC;
        __syncthreads();
        #pragma unroll
        for (int q = 0; q < 4; ++q) {          // stage z: 32 rows x 32 k
            int idx = q * 256 + tid;
            int row = idx >> 5, k = idx & 31;
            zT[k][row] = (double)z[(size_t)(g0 + row) * HD + k0 + k];
        }
        #pragma unroll
        for (int q = 0; q < 16; ++q) {         // stage W2: 128 cols x 32 k
            int idx = q * 256 + tid;
            int c = idx >> 5, k = idx & 31;
            wT[k][c] = (double)W2[(size_t)c * HD + k0 + k];
        }
        __syncthreads();
        #pragma unroll
        for (int k = 0; k < KC; ++k) {
            double zr[4], wr[4];
            #pragma unroll
            for (int i = 0; i < 4; ++i) zr[i] = zT[k][r0 + i];
            #pragma unroll
            for (int j = 0; j < 4; ++j) wr[j] = wT[k][tc + 32 * j];
            #pragma unroll
            for (int i = 0; i < 4; ++i)
                #pragma unroll
                for (int j = 0; j < 4; ++j)
                    acc[i][j] += zr[i] * wr[j];
        }
    }
    #pragma unroll
    for (int i = 0; i < 4; ++i)
        #pragma unroll
        for (int j = 0; j < 4; ++j)
            y[(size_t)(g0 + r0 + i) * HD + tc + 32 * j] = (float)acc[i][j];
}

// ---------------------------------------------------------------------------
// 10) edge stage (float4): u[b,e,f] = DE^-2 * sum_{v in e} y[b,v,f]*dvis[v].
//     128 threads = 32 float4-lanes x 4 batches; cnt float4 loads/thread
//     (4x fewer VMEM instrs than scalar). f64 accumulate (precision floor);
//     sum order over t unchanged -> bitwise-identical results.
// ---------------------------------------------------------------------------
__global__ void k_edge(const float4* __restrict__ y4, const double* __restrict__ dvis,
                       const int* __restrict__ knn1, const int* __restrict__ knn2,
                       float4* __restrict__ u4) {
    __shared__ int mem[19];
    __shared__ double wv[19];
    int e = blockIdx.x;
    int f4 = threadIdx.x & 31;      // float4 group (feature = 4*f4)
    int b  = threadIdx.x >> 5;      // batch
    int cnt;
    if      (e < NN)     cnt = 7;
    else if (e < 2 * NN) cnt = 19;
    else if (e < 3 * NN) cnt = 5;
    else if (e < 4 * NN) cnt = 13;
    else                 cnt = 2;
    int f = threadIdx.x;
    if (f < cnt) {
        int v;
        if      (e < NN)     v = knn1[(size_t)e * 19 + f];
        else if (e < 2 * NN) v = knn1[(size_t)(e - NN) * 19 + f];
        else if (e < 3 * NN) v = NN + knn2[(size_t)(e - 2 * NN) * 13 + f];
        else if (e < 4 * NN) v = NN + knn2[(size_t)(e - 3 * NN) * 13 + f];
        else                 v = (f == 0) ? (e - 4 * NN) : (e - 4 * NN + NN);
        mem[f] = v;
        wv[f] = dvis[v];
    }
    __syncthreads();
    const float4* yb = y4 + (size_t)b * TWO_N * 32;
    double ax = 0.0, ay = 0.0, az = 0.0, aw = 0.0;
    for (int t = 0; t < cnt; ++t) {
        double w = wv[t];
        float4 val = yb[(size_t)mem[t] * 32 + f4];
        ax += (double)val.x * w; ay += (double)val.y * w;
        az += (double)val.z * w; aw += (double)val.w * w;
    }
    double inv = 1.0 / (double)(cnt * cnt);
    u4[((size_t)b * NE + e) * 32 + f4] =
        make_float4((float)(ax * inv), (float)(ay * inv),
                    (float)(az * inv), (float)(aw * inv));
}

// ---------------------------------------------------------------------------
// 11) node stage (float4): z[b,v,f] = relu(dvis[v] * sum_{e in CSR[v]} u[b,e,f])
// ---------------------------------------------------------------------------
__global__ void k_node(const float4* __restrict__ u4, const double* __restrict__ dvis,
                       const int* __restrict__ offs, const int* __restrict__ entries,
                       float4* __restrict__ zbuf4, float4* __restrict__ outp4, int layer) {
    int v = blockIdx.x;
    int f4 = threadIdx.x & 31;
    int b  = threadIdx.x >> 5;
    int s = offs[v], e_end = offs[v + 1];
    const float4* ub = u4 + (size_t)b * NE * 32;
    double ax = 0.0, ay = 0.0, az = 0.0, aw = 0.0;
    for (int p = s; p < e_end; ++p) {
        int e = entries[p];               // broadcast load
        float4 val = ub[(size_t)e * 32 + f4];
        ax += (double)val.x; ay += (double)val.y;
        az += (double)val.z; aw += (double)val.w;
    }
    double dv = dvis[v];
    ax *= dv; ay *= dv; az *= dv; aw *= dv;
    if (ax < 0.0) ax = 0.0;
    if (ay < 0.0) ay = 0.0;
    if (az < 0.0) az = 0.0;
    if (aw < 0.0) aw = 0.0;
    float4 res = make_float4((float)ax, (float)ay, (float)az, (float)aw);
    if (layer == 0) {
        zbuf4[((size_t)b * TWO_N + v) * 32 + f4] = res;
    } else {
        size_t o;
        if (v < NN) o = ((size_t)(b * NN + v)) * 32 + f4;
        else        o = (size_t)BB * NN * 32 + ((size_t)(b * NN + (v - NN))) * 32 + f4;
        outp4[o] = res;
    }
}

// ---------------------------------------------------------------------------
extern "C" void kernel_launch(void* const* d_in, const int* in_sizes, int n_in,
                              void* d_out, int out_size, void* d_ws, size_t ws_size,
                              hipStream_t stream) {
    const float* f1 = (const float*)d_in[0];
    const float* f2 = (const float*)d_in[1];
    const float* W1 = (const float*)d_in[2];
    const float* W2 = (const float*)d_in[3];
    float* out = (float*)d_out;

    // bump allocator over d_ws (~72 MB)
    char* ws = (char*)d_ws;
    size_t off = 0;
    auto alloc = [&](size_t bytes) -> void* {
        void* p = ws + off;
        off = (off + bytes + 255) & ~(size_t)255;
        return p;
    };
    float*  g32T    = (float*)alloc((size_t)2 * CC * NN * 4);         // 1 MB
    double* gR64    = (double*)alloc((size_t)2 * NN * CC * 8);        // 2 MB
    float*  sims    = (float*)alloc((size_t)2 * NN * NN * 4);         // 32 MB
    float*  ybuf    = (float*)alloc((size_t)BB * TWO_N * HD * 4);     // 8 MB
    float*  zbuf    = (float*)alloc((size_t)BB * TWO_N * HD * 4);     // 8 MB
    float*  ubuf    = (float*)alloc((size_t)BB * NE * HD * 4);        // 20 MB
    double* dvis    = (double*)alloc((size_t)TWO_N * 8);
    int*    knn1    = (int*)alloc((size_t)NN * 19 * 4);
    int*    knn2    = (int*)alloc((size_t)NN * 13 * 4);
    int*    DV      = (int*)alloc((size_t)TWO_N * 4);
    int*    offs    = (int*)alloc((size_t)(TWO_N + 1) * 4);
    int*    cursor  = (int*)alloc((size_t)TWO_N * 4);
    int*    entries = (int*)alloc((size_t)NNZ * 4);
    int*    cand    = (int*)alloc((size_t)TWO_N * CANDCAP * 4);       // 512 KB
    int*    cntb    = (int*)alloc((size_t)TWO_N * 4);

    // graph construction: f32 sims + threshold-filter + provably-exact f64 refine
    k_mean_norm<<<dim3(NN, 2), 64, 0, stream>>>(f1, f2, g32T, gR64);
    k_sims<<<dim3(32 * 32, 2), 256, 0, stream>>>(g32T, sims);
    k_select<<<TWO_N / 8, 512, 0, stream>>>(sims, cand, cntb, DV);
    k_refine<<<TWO_N, 64, 0, stream>>>(gR64, cand, cntb, knn1, knn2, DV);
    k_scan<<<1, 64, 0, stream>>>(DV, offs, cursor, dvis);
    k_fill<<<(NN * 19 + NN * 13 + TWO_N + 255) / 256, 256, 0, stream>>>(knn1, knn2, cursor, entries);

    // layer 1
    k_gemm1<<<(BB * TWO_N) / 32, 256, 0, stream>>>(f1, f2, W1, ybuf);
    k_edge<<<NE, 128, 0, stream>>>((const float4*)ybuf, dvis, knn1, knn2, (float4*)ubuf);
    k_node<<<TWO_N, 128, 0, stream>>>((const float4*)ubuf, dvis, offs, entries,
                                      (float4*)zbuf, nullptr, 0);

    // layer 2
    k_gemm2<<<(BB * TWO_N) / 32, 256, 0, stream>>>(zbuf, W2, ybuf);
    k_edge<<<NE, 128, 0, stream>>>((const float4*)ybuf, dvis, knn1, knn2, (float4*)ubuf);
    k_node<<<TWO_N, 128, 0, stream>>>((const float4*)ubuf, dvis, offs, entries,
                                      nullptr, (float4*)out, 1);
}

// Round 10
// 243.314 us; speedup vs baseline: 4.7655x; 1.0464x over previous
//
#include <hip/hip_runtime.h>
#include <math.h>

// Problem constants
#define NN 2048      // nodes per modality
#define TWO_N 4096   // total nodes
#define NE 10240     // total hyperedges (5N)
#define BB 4         // batch
#define CC 64        // input feature dim
#define HD 128       // hidden dim
#define NNZ 94208    // 2048*(7+19) + 2048*(5+13) + 2*2048
#define CANDCAP 32   // max top-k candidates per row after f32 margin filter
#define KC 32        // gemm K-chunk

// Layouts: y/z buffers are v-major [v][b][f] (row id r' = v*4+b); u is [e][b][f].
// One edge-member gather = one contiguous 2 KB stream for the whole block.

// ---------------------------------------------------------------------------
// 1) batch-mean + L2-normalize.
// ---------------------------------------------------------------------------
__global__ void k_mean_norm(const float* __restrict__ f1, const float* __restrict__ f2,
                            float* __restrict__ g32T, double* __restrict__ gR64) {
    int n = blockIdx.x;           // node
    int m = blockIdx.y;           // modality
    int c = threadIdx.x;          // 64 threads = 1 wave
    const float* f = m ? f2 : f1;
    double s = 0.0;
    for (int b = 0; b < BB; ++b) s += (double)f[((size_t)(b * NN) + n) * CC + c];
    double mean = s * 0.25;
    double sq = mean * mean;
    for (int d = 32; d >= 1; d >>= 1) sq += __shfl_xor(sq, d);
    double norm = sqrt(sq);
    if (norm < 1e-12) norm = 1e-12;
    double g = mean / norm;
    g32T[((size_t)m * CC + c) * NN + n] = (float)g;
    gR64[((size_t)m * NN + n) * CC + c] = g;
}

// ---------------------------------------------------------------------------
// 2) f32 sims GEMM: sims[m] = G32 * G32^T  (2048x2048, K=64).
// ---------------------------------------------------------------------------
__global__ void __launch_bounds__(256)
k_sims(const float* __restrict__ g32T, float* __restrict__ sims) {
    __shared__ float As[CC][64];   // As[k][r], 16 KB
    __shared__ float Bs[CC][64];   // Bs[k][j], 16 KB
    int m  = blockIdx.y;
    int bi = blockIdx.x >> 5, bj = blockIdx.x & 31;
    int i0 = bi * 64, j0 = bj * 64;
    const float* g = g32T + (size_t)m * CC * NN;
    int tid = threadIdx.x;
    #pragma unroll
    for (int q = 0; q < 16; ++q) {
        int idx = q * 256 + tid;
        int k = idx >> 6, r = idx & 63;
        As[k][r] = g[(size_t)k * NN + i0 + r];
        Bs[k][r] = g[(size_t)k * NN + j0 + r];
    }
    __syncthreads();
    int tr = tid >> 4, tc = tid & 15;
    float acc[4][4] = {{0.f}};
    #pragma unroll
    for (int k = 0; k < CC; ++k) {
        float4 a = *((const float4*)&As[k][tr << 2]);
        float4 b = *((const float4*)&Bs[k][tc << 2]);
        acc[0][0] += a.x * b.x; acc[0][1] += a.x * b.y; acc[0][2] += a.x * b.z; acc[0][3] += a.x * b.w;
        acc[1][0] += a.y * b.x; acc[1][1] += a.y * b.y; acc[1][2] += a.y * b.z; acc[1][3] += a.y * b.w;
        acc[2][0] += a.z * b.x; acc[2][1] += a.z * b.y; acc[2][2] += a.z * b.z; acc[2][3] += a.z * b.w;
        acc[3][0] += a.w * b.x; acc[3][1] += a.w * b.y; acc[3][2] += a.w * b.z; acc[3][3] += a.w * b.w;
    }
    float* srow = sims + (size_t)m * NN * NN;
    #pragma unroll
    for (int x = 0; x < 4; ++x) {
        float4 v = make_float4(acc[x][0], acc[x][1], acc[x][2], acc[x][3]);
        *((float4*)&srow[(size_t)(i0 + (tr << 2) + x) * NN + j0 + (tc << 2)]) = v;
    }
}

// ---------------------------------------------------------------------------
// 3) f32 threshold + margin candidate capture (binary-search ballot count).
//    Also inits DV[row]=1 (inter edge).
// ---------------------------------------------------------------------------
__global__ void __launch_bounds__(512)
k_select(const float* __restrict__ sims, int* __restrict__ cand, int* __restrict__ cntb,
         int* __restrict__ DV) {
    int wave = threadIdx.x >> 6, lane = threadIdx.x & 63;
    int row = blockIdx.x * 8 + wave;    // 0..4095
    int m = row >> 11, i = row & 2047;
    int K = m ? 13 : 19;
    const float* s = sims + (size_t)m * NN * NN + (size_t)i * NN;
    float sv[32];
    #pragma unroll
    for (int q = 0; q < 8; ++q) {
        float4 v = *((const float4*)&s[q * 256 + (lane << 2)]);
        sv[q * 4 + 0] = v.x; sv[q * 4 + 1] = v.y; sv[q * 4 + 2] = v.z; sv[q * 4 + 3] = v.w;
    }
    float lo = -1.01f, hi = 1.01f;     // cosine sims live in [-1,1]
    for (int it = 0; it < 20; ++it) {
        float t = 0.5f * (lo + hi);
        int cnt = 0;
        #pragma unroll
        for (int r = 0; r < 32; ++r)
            cnt += __popcll(__ballot(sv[r] >= t));
        if (cnt >= K) lo = t; else hi = t;   // wave-uniform branch
    }
    float thr = lo - 1e-5f;
    unsigned long long ltmask = (lane == 0) ? 0ull : ((~0ull) >> (64 - lane));
    int base = 0;
    int* crow = cand + (size_t)row * CANDCAP;
    #pragma unroll
    for (int r = 0; r < 32; ++r) {
        int j = ((r >> 2) << 8) + (lane << 2) + (r & 3);
        bool p = sv[r] >= thr;
        unsigned long long mk = __ballot(p);
        int ofs = base + __popcll(mk & ltmask);
        if (p && ofs < CANDCAP) crow[ofs] = j;
        base += __popcll(mk);
    }
    if (lane == 0) {
        cntb[row] = (base < CANDCAP) ? base : CANDCAP;
        DV[row] = 1;                        // inter-edge contribution
    }
}

// ---------------------------------------------------------------------------
// 4) exact f64 refine + degree count.
// ---------------------------------------------------------------------------
__global__ void k_refine(const double* __restrict__ gR64,
                         const int* __restrict__ cand, const int* __restrict__ cntb,
                         int* __restrict__ knn1, int* __restrict__ knn2,
                         int* __restrict__ DV) {
    __shared__ double dots[CANDCAP];
    int row = blockIdx.x, lane = threadIdx.x;   // 64 threads
    int m = row >> 11, i = row & 2047;
    int K = m ? 13 : 19;
    int cnt = cntb[row]; if (cnt > CANDCAP) cnt = CANDCAP;
    const double* gm = gR64 + (size_t)m * NN * CC;
    const int* crow = cand + (size_t)row * CANDCAP;
    double qc = gm[(size_t)i * CC + lane];
    for (int t = 0; t < cnt; ++t) {
        int j = crow[t];
        double p = qc * gm[(size_t)j * CC + lane];
        #pragma unroll
        for (int d = 32; d >= 1; d >>= 1) p += __shfl_xor(p, d);
        if (lane == 0) dots[t] = p;
    }
    __syncthreads();
    int* knn = m ? knn2 : knn1;
    if (lane < cnt) {
        double vt = dots[lane]; int jt = crow[lane];
        int rank = 0;
        for (int s = 0; s < cnt; ++s) {
            double vs = dots[s]; int js = crow[s];
            if (vs > vt || (vs == vt && js < jt)) ++rank;
        }
        if (rank < K) {
            knn[(size_t)i * K + rank] = jt;
            int w = (rank < (m ? 5 : 7)) ? 2 : 1;
            atomicAdd(&DV[m ? NN + jt : jt], w);
        }
    }
}

// ---------------------------------------------------------------------------
// 6) exclusive scan of DV -> CSR offsets; cursor copy; dvis = 1/sqrt(DV)
// ---------------------------------------------------------------------------
__global__ void k_scan(const int* __restrict__ DV, int* __restrict__ offs,
                       int* __restrict__ cursor, double* __restrict__ dvis) {
    int lane = threadIdx.x;      // 64
    int base = lane * 64;
    int s = 0;
    for (int q = 0; q < 64; ++q) s += DV[base + q];
    int x = s;
    for (int d = 1; d < 64; d <<= 1) {
        int y = __shfl_up(x, d);
        if (lane >= d) x += y;
    }
    int run = x - s;             // exclusive prefix of lane chunk
    for (int q = 0; q < 64; ++q) {
        int v = base + q;
        offs[v] = run; cursor[v] = run;
        dvis[v] = 1.0 / sqrt((double)DV[v]);
        run += DV[v];
    }
    if (lane == 63) offs[TWO_N] = run;   // == NNZ
}

// ---------------------------------------------------------------------------
// 7) fill CSR transpose: node v -> list of edge ids containing v
// ---------------------------------------------------------------------------
__global__ void k_fill(const int* __restrict__ knn1, const int* __restrict__ knn2,
                       int* __restrict__ cursor, int* __restrict__ entries) {
    int id = blockIdx.x * blockDim.x + threadIdx.x;
    const int M1 = NN * 19, M2 = NN * 13;
    if (id < M1) {
        int i = id / 19, t = id % 19;
        int v = knn1[id];
        int p = atomicAdd(&cursor[v], 1); entries[p] = NN + i;       // k=18 edge
        if (t < 7) { int p2 = atomicAdd(&cursor[v], 1); entries[p2] = i; }
    } else if (id < M1 + M2) {
        int id2 = id - M1;
        int i = id2 / 13, t = id2 % 13;
        int v = NN + knn2[id2];
        int p = atomicAdd(&cursor[v], 1); entries[p] = 3 * NN + i;   // k=12 edge
        if (t < 5) { int p2 = atomicAdd(&cursor[v], 1); entries[p2] = 2 * NN + i; }
    } else if (id < M1 + M2 + TWO_N) {
        int v = id - (M1 + M2);
        int i = (v < NN) ? v : (v - NN);
        int p = atomicAdd(&cursor[v], 1); entries[p] = 4 * NN + i;   // inter edge
    }
}

// ---------------------------------------------------------------------------
// 8) y = x @ W1^T (K=64). Register-tiled f64; rows are v-major (r' = v*4+b).
// ---------------------------------------------------------------------------
__global__ void __launch_bounds__(256)
k_gemm1(const float* __restrict__ f1, const float* __restrict__ f2,
        const float* __restrict__ W1, float* __restrict__ y) {
    __shared__ double xT[KC][33];    // [k][row] +1 pad
    __shared__ double wT[KC][130];   // [k][col] +2 pad
    int tid = threadIdx.x;
    int g0 = blockIdx.x * 32;        // r' base; 8 nodes x 4 batches per block
    int tr = tid >> 5, tc = tid & 31;
    int r0 = tr * 4;
    double acc[4][4] = {{0.0}};
    for (int kc = 0; kc < CC / KC; ++kc) {
        int k0 = kc * KC;
        __syncthreads();
        #pragma unroll
        for (int q = 0; q < 4; ++q) {          // stage x: 32 rows x 32 k
            int idx = q * 256 + tid;
            int row = idx >> 5, k = idx & 31;
            int rp = g0 + row, v = rp >> 2, b = rp & 3;   // v-major
            const float* src = (v < NN) ? &f1[((size_t)(b * NN) + v) * CC]
                                        : &f2[((size_t)(b * NN) + (v - NN)) * CC];
            xT[k][row] = (double)src[k0 + k];
        }
        #pragma unroll
        for (int q = 0; q < 16; ++q) {         // stage W1: 128 cols x 32 k
            int idx = q * 256 + tid;
            int c = idx >> 5, k = idx & 31;
            wT[k][c] = (double)W1[(size_t)c * CC + k0 + k];
        }
        __syncthreads();
        #pragma unroll
        for (int k = 0; k < KC; ++k) {
            double xr[4], wr[4];
            #pragma unroll
            for (int i = 0; i < 4; ++i) xr[i] = xT[k][r0 + i];
            #pragma unroll
            for (int j = 0; j < 4; ++j) wr[j] = wT[k][tc + 32 * j];
            #pragma unroll
            for (int i = 0; i < 4; ++i)
                #pragma unroll
                for (int j = 0; j < 4; ++j)
                    acc[i][j] += xr[i] * wr[j];
        }
    }
    #pragma unroll
    for (int i = 0; i < 4; ++i)
        #pragma unroll
        for (int j = 0; j < 4; ++j)
            y[(size_t)(g0 + r0 + i) * HD + tc + 32 * j] = (float)acc[i][j];
}

// ---------------------------------------------------------------------------
// 9) y = z @ W2^T (K=128). Rows v-major; indexing identical to before.
// ---------------------------------------------------------------------------
__global__ void __launch_bounds__(256)
k_gemm2(const float* __restrict__ z, const float* __restrict__ W2,
        float* __restrict__ y) {
    __shared__ double zT[KC][33];
    __shared__ double wT[KC][130];
    int tid = threadIdx.x;
    int g0 = blockIdx.x * 32;
    int tr = tid >> 5, tc = tid & 31;
    int r0 = tr * 4;
    double acc[4][4] = {{0.0}};
    for (int kc = 0; kc < HD / KC; ++kc) {
        int k0 = kc * KC;
        __syncthreads();
        #pragma unroll
        for (int q = 0; q < 4; ++q) {          // stage z: 32 rows x 32 k
            int idx = q * 256 + tid;
            int row = idx >> 5, k = idx & 31;
            zT[k][row] = (double)z[(size_t)(g0 + row) * HD + k0 + k];
        }
        #pragma unroll
        for (int q = 0; q < 16; ++q) {         // stage W2: 128 cols x 32 k
            int idx = q * 256 + tid;
            int c = idx >> 5, k = idx & 31;
            wT[k][c] = (double)W2[(size_t)c * HD + k0 + k];
        }
        __syncthreads();
        #pragma unroll
        for (int k = 0; k < KC; ++k) {
            double zr[4], wr[4];
            #pragma unroll
            for (int i = 0; i < 4; ++i) zr[i] = zT[k][r0 + i];
            #pragma unroll
            for (int j = 0; j < 4; ++j) wr[j] = wT[k][tc + 32 * j];
            #pragma unroll
            for (int i = 0; i < 4; ++i)
                #pragma unroll
                for (int j = 0; j < 4; ++j)
                    acc[i][j] += zr[i] * wr[j];
        }
    }
    #pragma unroll
    for (int i = 0; i < 4; ++i)
        #pragma unroll
        for (int j = 0; j < 4; ++j)
            y[(size_t)(g0 + r0 + i) * HD + tc + 32 * j] = (float)acc[i][j];
}

// ---------------------------------------------------------------------------
// 10) edge stage, PAIRED (prefix-sharing): top-k members of the small-k edge
//     are a prefix of the big-k edge's members. One block computes both.
//     Grid 6144: [0,NN) m1 pairs; [NN,2NN) m2 pairs; [2NN,3NN) inter edges.
//     Member traffic 94208 -> 69632 gathers (-26%).
// ---------------------------------------------------------------------------
__global__ void k_edge(const float4* __restrict__ y4, const double* __restrict__ dvis,
                       const int* __restrict__ knn1, const int* __restrict__ knn2,
                       float4* __restrict__ u4) {
    __shared__ int mem[19];
    __shared__ double wv[19];
    int blk = blockIdx.x;
    int f4 = threadIdx.x & 31;      // float4 feature group
    int b  = threadIdx.x >> 5;      // batch
    int bo = b * 32 + f4;
    int t = threadIdx.x;
    if (blk < NN) {                 // modality-1 pair: k6 (7 members) + k18 (19)
        if (t < 19) { int v = knn1[(size_t)blk * 19 + t]; mem[t] = v; wv[t] = dvis[v]; }
        __syncthreads();
        double ax = 0, ay = 0, az = 0, aw = 0;
        #pragma unroll
        for (int q = 0; q < 7; ++q) {
            double w = wv[q];
            float4 val = y4[(size_t)mem[q] * 128 + bo];
            ax += (double)val.x * w; ay += (double)val.y * w;
            az += (double)val.z * w; aw += (double)val.w * w;
        }
        const double i7 = 1.0 / 49.0;
        u4[(size_t)blk * 128 + bo] =
            make_float4((float)(ax * i7), (float)(ay * i7), (float)(az * i7), (float)(aw * i7));
        #pragma unroll
        for (int q = 7; q < 19; ++q) {
            double w = wv[q];
            float4 val = y4[(size_t)mem[q] * 128 + bo];
            ax += (double)val.x * w; ay += (double)val.y * w;
            az += (double)val.z * w; aw += (double)val.w * w;
        }
        const double i19 = 1.0 / 361.0;
        u4[(size_t)(NN + blk) * 128 + bo] =
            make_float4((float)(ax * i19), (float)(ay * i19), (float)(az * i19), (float)(aw * i19));
    } else if (blk < 2 * NN) {      // modality-2 pair: k4 (5 members) + k12 (13)
        int i = blk - NN;
        if (t < 13) { int v = NN + knn2[(size_t)i * 13 + t]; mem[t] = v; wv[t] = dvis[v]; }
        __syncthreads();
        double ax = 0, ay = 0, az = 0, aw = 0;
        #pragma unroll
        for (int q = 0; q < 5; ++q) {
            double w = wv[q];
            float4 val = y4[(size_t)mem[q] * 128 + bo];
            ax += (double)val.x * w; ay += (double)val.y * w;
            az += (double)val.z * w; aw += (double)val.w * w;
        }
        const double i5 = 1.0 / 25.0;
        u4[(size_t)(2 * NN + i) * 128 + bo] =
            make_float4((float)(ax * i5), (float)(ay * i5), (float)(az * i5), (float)(aw * i5));
        #pragma unroll
        for (int q = 5; q < 13; ++q) {
            double w = wv[q];
            float4 val = y4[(size_t)mem[q] * 128 + bo];
            ax += (double)val.x * w; ay += (double)val.y * w;
            az += (double)val.z * w; aw += (double)val.w * w;
        }
        const double i13 = 1.0 / 169.0;
        u4[(size_t)(3 * NN + i) * 128 + bo] =
            make_float4((float)(ax * i13), (float)(ay * i13), (float)(az * i13), (float)(aw * i13));
    } else {                        // inter edge: members v, v+NN
        int i = blk - 2 * NN;
        double w0 = dvis[i], w1 = dvis[NN + i];
        float4 a = y4[(size_t)i * 128 + bo];
        float4 c = y4[(size_t)(NN + i) * 128 + bo];
        u4[(size_t)(4 * NN + i) * 128 + bo] =
            make_float4((float)(((double)a.x * w0 + (double)c.x * w1) * 0.25),
                        (float)(((double)a.y * w0 + (double)c.y * w1) * 0.25),
                        (float)(((double)a.z * w0 + (double)c.z * w1) * 0.25),
                        (float)(((double)a.w * w0 + (double)c.w * w1) * 0.25));
    }
}

// ---------------------------------------------------------------------------
// 11) node stage: z[v,b,f] = relu(dvis[v] * sum_{e in CSR[v]} u[e,b,f]).
//     2-way unrolled p-loop: 8 independent f64 chains, more loads in flight.
// ---------------------------------------------------------------------------
__global__ void k_node(const float4* __restrict__ u4, const double* __restrict__ dvis,
                       const int* __restrict__ offs, const int* __restrict__ entries,
                       float4* __restrict__ zbuf4, float4* __restrict__ outp4, int layer) {
    int v = blockIdx.x;
    int f4 = threadIdx.x & 31;
    int b  = threadIdx.x >> 5;
    int bo = b * 32 + f4;
    int s = offs[v], e_end = offs[v + 1];
    double ax = 0, ay = 0, az = 0, aw = 0;
    double cx = 0, cy = 0, cz = 0, cw = 0;
    int p = s;
    for (; p + 1 < e_end; p += 2) {
        int e0 = entries[p], e1 = entries[p + 1];
        float4 v0 = u4[(size_t)e0 * 128 + bo];
        float4 v1 = u4[(size_t)e1 * 128 + bo];
        ax += v0.x; ay += v0.y; az += v0.z; aw += v0.w;
        cx += v1.x; cy += v1.y; cz += v1.z; cw += v1.w;
    }
    if (p < e_end) {
        float4 v0 = u4[(size_t)entries[p] * 128 + bo];
        ax += v0.x; ay += v0.y; az += v0.z; aw += v0.w;
    }
    ax += cx; ay += cy; az += cz; aw += cw;
    double dv = dvis[v];
    ax *= dv; ay *= dv; az *= dv; aw *= dv;
    if (ax < 0.0) ax = 0.0;
    if (ay < 0.0) ay = 0.0;
    if (az < 0.0) az = 0.0;
    if (aw < 0.0) aw = 0.0;
    float4 res = make_float4((float)ax, (float)ay, (float)az, (float)aw);
    if (layer == 0) {
        zbuf4[((size_t)v * 4 + b) * 32 + f4] = res;      // v-major
    } else {
        size_t o;
        if (v < NN) o = ((size_t)(b * NN + v)) * 32 + f4;
        else        o = (size_t)BB * NN * 32 + ((size_t)(b * NN + (v - NN))) * 32 + f4;
        outp4[o] = res;
    }
}

// ---------------------------------------------------------------------------
extern "C" void kernel_launch(void* const* d_in, const int* in_sizes, int n_in,
                              void* d_out, int out_size, void* d_ws, size_t ws_size,
                              hipStream_t stream) {
    const float* f1 = (const float*)d_in[0];
    const float* f2 = (const float*)d_in[1];
    const float* W1 = (const float*)d_in[2];
    const float* W2 = (const float*)d_in[3];
    float* out = (float*)d_out;

    // bump allocator over d_ws (~72 MB)
    char* ws = (char*)d_ws;
    size_t off = 0;
    auto alloc = [&](size_t bytes) -> void* {
        void* p = ws + off;
        off = (off + bytes + 255) & ~(size_t)255;
        return p;
    };
    float*  g32T    = (float*)alloc((size_t)2 * CC * NN * 4);         // 1 MB
    double* gR64    = (double*)alloc((size_t)2 * NN * CC * 8);        // 2 MB
    float*  sims    = (float*)alloc((size_t)2 * NN * NN * 4);         // 32 MB
    float*  ybuf    = (float*)alloc((size_t)BB * TWO_N * HD * 4);     // 8 MB  (v-major)
    float*  zbuf    = (float*)alloc((size_t)BB * TWO_N * HD * 4);     // 8 MB  (v-major)
    float*  ubuf    = (float*)alloc((size_t)BB * NE * HD * 4);        // 20 MB (e-major)
    double* dvis    = (double*)alloc((size_t)TWO_N * 8);
    int*    knn1    = (int*)alloc((size_t)NN * 19 * 4);
    int*    knn2    = (int*)alloc((size_t)NN * 13 * 4);
    int*    DV      = (int*)alloc((size_t)TWO_N * 4);
    int*    offs    = (int*)alloc((size_t)(TWO_N + 1) * 4);
    int*    cursor  = (int*)alloc((size_t)TWO_N * 4);
    int*    entries = (int*)alloc((size_t)NNZ * 4);
    int*    cand    = (int*)alloc((size_t)TWO_N * CANDCAP * 4);       // 512 KB
    int*    cntb    = (int*)alloc((size_t)TWO_N * 4);

    // graph construction: f32 sims + threshold-filter + provably-exact f64 refine
    k_mean_norm<<<dim3(NN, 2), 64, 0, stream>>>(f1, f2, g32T, gR64);
    k_sims<<<dim3(32 * 32, 2), 256, 0, stream>>>(g32T, sims);
    k_select<<<TWO_N / 8, 512, 0, stream>>>(sims, cand, cntb, DV);
    k_refine<<<TWO_N, 64, 0, stream>>>(gR64, cand, cntb, knn1, knn2, DV);
    k_scan<<<1, 64, 0, stream>>>(DV, offs, cursor, dvis);
    k_fill<<<(NN * 19 + NN * 13 + TWO_N + 255) / 256, 256, 0, stream>>>(knn1, knn2, cursor, entries);

    // layer 1
    k_gemm1<<<(BB * TWO_N) / 32, 256, 0, stream>>>(f1, f2, W1, ybuf);
    k_edge<<<3 * NN, 128, 0, stream>>>((const float4*)ybuf, dvis, knn1, knn2, (float4*)ubuf);
    k_node<<<TWO_N, 128, 0, stream>>>((const float4*)ubuf, dvis, offs, entries,
                                      (float4*)zbuf, nullptr, 0);

    // layer 2
    k_gemm2<<<(BB * TWO_N) / 32, 256, 0, stream>>>(zbuf, W2, ybuf);
    k_edge<<<3 * NN, 128, 0, stream>>>((const float4*)ybuf, dvis, knn1, knn2, (float4*)ubuf);
    k_node<<<TWO_N, 128, 0, stream>>>((const float4*)ubuf, dvis, offs, entries,
                                      nullptr, (float4*)out, 1);
}